// Round 5
// baseline (3088.505 us; speedup 1.0000x reference)
//
#include <hip/hip_runtime.h>
#include <stdint.h>

typedef __bf16 bf16_t;
typedef __attribute__((ext_vector_type(8))) __bf16 bf16x8;
typedef __attribute__((ext_vector_type(4))) __bf16 bf16x4;
typedef __attribute__((ext_vector_type(4))) float f32x4;

#define NB 32
#define NS 2048
#define ND 1024
#define NV 32000
#define SP 2050       // padded rows per batch for conv (1 zero row each side)
#define MCHUNK 32768  // max rows per fused tree-GEMM chunk (201MB bf16 logits)

__device__ __forceinline__ float sigmoid_(float x) { return 1.0f / (1.0f + __expf(-x)); }

__device__ __forceinline__ void gload_lds16(const void* g, void* lds) {
  __builtin_amdgcn_global_load_lds((const __attribute__((address_space(1))) void*)g,
                                   (__attribute__((address_space(3))) void*)lds, 16, 0, 0);
}

// ---------------- prep / elementwise kernels ----------------

__global__ void zero_pad_k(bf16_t* h0p) {
  int i = blockIdx.x;  // 0..63 : 2 pad rows per batch
  int b = i >> 1;
  size_t row = (size_t)b * SP + ((i & 1) ? (SP - 1) : 0);
  bf16x4 z = {};
  *(bf16x4*)(h0p + row * ND + threadIdx.x * 4) = z;
}

__global__ void embed_k(const int* __restrict__ x, const float* __restrict__ emb,
                        const float* __restrict__ pos, bf16_t* __restrict__ h0p) {
  int bs = blockIdx.x;  // 0..NB*NS-1
  int b = bs >> 11, s = bs & (NS - 1);
  int idx = x[bs];
  const float* e = emb + (size_t)idx * ND;
  const float* p = pos + (size_t)s * ND;
  bf16_t* o = h0p + ((size_t)b * SP + s + 1) * ND;
  int d = threadIdx.x * 4;
  f32x4 ev = *(const f32x4*)(e + d);
  f32x4 pv = *(const f32x4*)(p + d);
  bf16x4 ov;
  ov[0] = (bf16_t)(ev[0] + pv[0]);
  ov[1] = (bf16_t)(ev[1] + pv[1]);
  ov[2] = (bf16_t)(ev[2] + pv[2]);
  ov[3] = (bf16_t)(ev[3] + pv[3]);
  *(bf16x4*)(o + d) = ov;
}

// f32 (R x C) -> bf16 (C x R) transpose+convert, 32x32 LDS tiles
__global__ void conv_transpose_k(const float* __restrict__ in, bf16_t* __restrict__ out,
                                 int R, int C) {
  __shared__ float tile[32][33];
  int tc = blockIdx.x * 32, tr = blockIdx.y * 32;
  int tx = threadIdx.x;
  for (int i = threadIdx.y; i < 32; i += 8)
    tile[i][tx] = in[(size_t)(tr + i) * C + tc + tx];
  __syncthreads();
  for (int i = threadIdx.y; i < 32; i += 8)
    out[(size_t)(tc + i) * R + tr + tx] = (bf16_t)tile[tx][i];
}

__global__ void dup_row_k(bf16_t* nodes) {
  int b = blockIdx.x;
  const bf16_t* src = nodes + ((size_t)b * NS + NS - 2) * ND;
  bf16_t* dst = nodes + ((size_t)b * NS + NS - 1) * ND;
  int d = threadIdx.x * 4;
  *(bf16x4*)(dst + d) = *(const bf16x4*)(src + d);
}

__global__ void concat3_k(const float* __restrict__ a, const float* __restrict__ b,
                          const float* __restrict__ c, float* __restrict__ o) {
  int i = blockIdx.x * 256 + threadIdx.x;  // 0..3071
  o[i] = i < 1024 ? a[i] : (i < 2048 ? b[i - 1024] : c[i - 2048]);
}

// ---------------- 256x256 8-phase GEMM: C = A(MxK, lda) @ Bt(NxK)^T + bias ----------
// BK=64, 512 threads = 8 waves (2M x 4N), per-wave C = 128x64, acc[8][4].
// LDS 128KB: sA/sB[2][256][64] bf16, XOR chunk swizzle (stored chunk c holds
// logical chunk c ^ (row&7)); staged via pre-swizzled global source, linear dest.
// Per K-tile t (buf = t&1), 4 phases:
//   p0: ds_read B-frags(8) + A-chunk0(4); stage A(t+1) both halves -> buf^1
//   p1: A-chunk1; stage B-lo(t+2) -> buf     p2: A-chunk2; stage B-hi(t+2) -> buf
//   p3: A-chunk3; boundary: s_waitcnt vmcnt(4) (B(t+2) stays in flight) + barrier
// Each phase: reads ; stages ; s_barrier ; setprio(1) 16xMFMA setprio(0) ; s_barrier.
// WAR-safe: stage targets are fully consumed >=1 phase before issue (see ledger).
// EPI 0: bf16   1: bf16 aux*sigmoid(v) (GLU)   3: bf16 tree logits
//   (EPI 3: col<1024 -> v (val), else sigmoid(v) (gates))
template <int EPI>
__global__ __launch_bounds__(512, 2) void gemm256(
    const bf16_t* __restrict__ A, const bf16_t* __restrict__ Bt,
    const float* __restrict__ bias, const void* aux, void* Cout,
    int M, int N, int K, int lda, int batchShift, int batchPad,
    int GX, int gpx, int nxg, int ych) {
  const int tid = threadIdx.x;
  const int lane = tid & 63;
  const int wave = tid >> 6;
  int n0, m0;
  if (nxg == 0) {  // linear mapping for small grids
    n0 = (blockIdx.x % GX) * 256;
    m0 = (blockIdx.x / GX) * 256;
  } else {  // XCD-partition: xcd owns gpx N-panels + contiguous Y slice
    const int id = blockIdx.x;
    const int xcd = id & 7;
    const int jb = id >> 3;
    const int xg = xcd % nxg;
    const int ysub = xcd / nxg;
    n0 = (xg * gpx + (jb % gpx)) * 256;
    m0 = (ysub * ych + (jb / gpx)) * 256;
  }
  const int waveM = wave >> 2, waveN = wave & 3;

  __shared__ __align__(16) bf16_t sA[2][256 * 64];
  __shared__ __align__(16) bf16_t sB[2][256 * 64];

  f32x4 acc[8][4] = {};

  const int srow = tid >> 3;  // 0..63
  const int sj = tid & 7;
  const int wbase = wave * 8;

  auto stageA = [&](int buf, int kt, int half) {
#pragma unroll
    for (int r = 0; r < 2; ++r) {
      int lr = half * 128 + r * 64 + srow;  // tile row 0..255
      int sc = sj ^ (lr & 7);               // pre-swizzled source chunk
      int g = m0 + lr;
      if (g > M - 1) g = M - 1;
      size_t grow = (size_t)g + (size_t)(((unsigned)g) >> batchShift) * batchPad;
      gload_lds16(A + grow * (size_t)lda + (kt * 64 + sc * 8),
                  &sA[buf][(size_t)(half * 128 + r * 64 + wbase) * 64]);
    }
  };
  auto stageB = [&](int buf, int kt, int half) {
#pragma unroll
    for (int r = 0; r < 2; ++r) {
      int lr = half * 128 + r * 64 + srow;
      int sc = sj ^ (lr & 7);
      int g = n0 + lr;
      if (g > N - 1) g = N - 1;
      gload_lds16(Bt + (size_t)g * K + (kt * 64 + sc * 8),
                  &sB[buf][(size_t)(half * 128 + r * 64 + wbase) * 64]);
    }
  };

  const int nt = K >> 6;
  // prologue: A(0), B(0) -> buf0; B(1) -> buf1; wait A(0)+B(0) landed
  stageA(0, 0, 0); stageA(0, 0, 1);
  stageB(0, 0, 0); stageB(0, 0, 1);
  if (nt > 1) {
    stageB(1, 1, 0); stageB(1, 1, 1);
    asm volatile("s_waitcnt vmcnt(4)" ::: "memory");
  } else {
    asm volatile("s_waitcnt vmcnt(0)" ::: "memory");
  }
  __builtin_amdgcn_s_barrier();

  const int rlane = lane & 15;
  const int klane = lane >> 4;
  bf16x8 bfr[4][2];

  for (int t = 0; t < nt; ++t) {
    const int buf = t & 1;
    const bf16_t* sa = sA[buf];
    const bf16_t* sb = sB[buf];
#pragma unroll
    for (int p = 0; p < 4; ++p) {
      // ---- ds_read section ----
      if (p == 0) {
#pragma unroll
        for (int j = 0; j < 4; ++j)
#pragma unroll
          for (int ks = 0; ks < 2; ++ks) {
            int rb = waveN * 64 + j * 16 + rlane;
            int kc = ks * 4 + klane;
            bfr[j][ks] = *(const bf16x8*)&sb[rb * 64 + ((kc ^ (rb & 7)) * 8)];
          }
      }
      bf16x8 af[2][2];
#pragma unroll
      for (int ii = 0; ii < 2; ++ii)
#pragma unroll
        for (int ks = 0; ks < 2; ++ks) {
          int ra = waveM * 128 + p * 32 + ii * 16 + rlane;
          int kc = ks * 4 + klane;
          af[ii][ks] = *(const bf16x8*)&sa[ra * 64 + ((kc ^ (ra & 7)) * 8)];
        }
      // ---- stage section ----
      if (p == 0) {
        if (t + 1 < nt) { stageA(buf ^ 1, t + 1, 0); stageA(buf ^ 1, t + 1, 1); }
      } else if (p == 1) {
        if (t + 2 < nt) stageB(buf, t + 2, 0);
      } else if (p == 2) {
        if (t + 2 < nt) stageB(buf, t + 2, 1);
      }
      __builtin_amdgcn_s_barrier();
      // ---- MFMA cluster ----
      __builtin_amdgcn_s_setprio(1);
#pragma unroll
      for (int ks = 0; ks < 2; ++ks)
#pragma unroll
        for (int ii = 0; ii < 2; ++ii)
#pragma unroll
          for (int j = 0; j < 4; ++j)
            acc[p * 2 + ii][j] = __builtin_amdgcn_mfma_f32_16x16x32_bf16(
                af[ii][ks], bfr[j][ks], acc[p * 2 + ii][j], 0, 0, 0);
      __builtin_amdgcn_s_setprio(0);
      if (p < 3) {
        __builtin_amdgcn_s_barrier();
      } else {
        if (t + 2 < nt)
          asm volatile("s_waitcnt vmcnt(4)" ::: "memory");
        else
          asm volatile("s_waitcnt vmcnt(0)" ::: "memory");
        __builtin_amdgcn_s_barrier();
      }
    }
  }

  // ---- epilogue ----
  const int colBase = n0 + waveN * 64 + rlane;
#pragma unroll
  for (int i = 0; i < 8; ++i) {
    const int rowBase = m0 + waveM * 128 + i * 16 + klane * 4;
#pragma unroll
    for (int j = 0; j < 4; ++j) {
      const int col = colBase + j * 16;
      const float bv = bias[col];
#pragma unroll
      for (int r = 0; r < 4; ++r) {
        const int row = rowBase + r;
        if (row >= M) continue;
        float v = acc[i][j][r] + bv;
        size_t o = (size_t)row * N + col;
        if constexpr (EPI == 0) {
          ((bf16_t*)Cout)[o] = (bf16_t)v;
        } else if constexpr (EPI == 1) {
          float hh = (float)((const bf16_t*)aux)[o];
          ((bf16_t*)Cout)[o] = (bf16_t)(hh * sigmoid_(v));
        } else {
          ((bf16_t*)Cout)[o] = (bf16_t)(col < 1024 ? v : sigmoid_(v));
        }
      }
    }
  }
}

// ---------------- tree combine: rmsnorm + gated mix from bf16 fused logits ----------------
// fb row: [0,1024) = val, [1024,2048) = sigmoid(mg), [2048,3072) = sigmoid(rg)
__global__ __launch_bounds__(256) void tree_combine_k(
    const bf16_t* __restrict__ fb, const bf16_t* __restrict__ cur,
    const float* __restrict__ rms_w, bf16_t* __restrict__ outb) {
  const int m = blockIdx.x;
  const int t = threadIdx.x;
  const int d = t * 4;
  const bf16_t* row = fb + (size_t)m * 3072;
  bf16x4 vb = *(const bf16x4*)(row + d);
  bf16x4 gb = *(const bf16x4*)(row + 1024 + d);
  bf16x4 rb = *(const bf16x4*)(row + 2048 + d);
  f32x4 vg;
#pragma unroll
  for (int k = 0; k < 4; ++k) vg[k] = (float)vb[k] * (float)gb[k];
  float ss = vg[0] * vg[0] + vg[1] * vg[1] + vg[2] * vg[2] + vg[3] * vg[3];
#pragma unroll
  for (int o = 32; o > 0; o >>= 1) ss += __shfl_xor(ss, o);
  __shared__ float red[4];
  if ((t & 63) == 0) red[t >> 6] = ss;
  __syncthreads();
  float ms = (red[0] + red[1] + red[2] + red[3]) * (1.0f / ND);
  float scale = rsqrtf(ms + 1.1920929e-07f);
  f32x4 w = *(const f32x4*)(rms_w + d);
  const bf16_t* c0 = cur + (size_t)m * 2048;
  bf16x4 lv = *(const bf16x4*)(c0 + d);
  bf16x4 rv = *(const bf16x4*)(c0 + ND + d);
  bf16x4 o4;
#pragma unroll
  for (int k = 0; k < 4; ++k) {
    float merged = vg[k] * scale * w[k];
    float resid = 0.5f * ((float)lv[k] + (float)rv[k]);
    float g = (float)rb[k];
    o4[k] = (bf16_t)(g * merged + (1.0f - g) * resid);
  }
  *(bf16x4*)(outb + (size_t)m * ND + d) = o4;
}

__global__ void build_ctx_k(const bf16_t* __restrict__ root, const bf16_t* __restrict__ nodes,
                            float* __restrict__ ctx) {
  int b = blockIdx.x, t = threadIdx.x;
  const bf16_t* r = root + (size_t)b * ND;
  const bf16_t* l = nodes + ((size_t)b * NS + NS - 2) * ND;
  int d = t * 4;
#pragma unroll
  for (int k = 0; k < 4; ++k) {
    ctx[(size_t)b * 2048 + d + k] = (float)r[d + k];
    ctx[(size_t)b * 2048 + ND + d + k] = (float)l[d + k];
  }
}

// ---------------- final projection in f32: out[b,v] = ctx[b,:]@wp[:,v] + bp[v] ----------------
__global__ __launch_bounds__(256) void final_proj_k(
    const float* __restrict__ ctx, const float* __restrict__ wp,
    const float* __restrict__ bp, float* __restrict__ out) {
  const int v = blockIdx.x * 256 + threadIdx.x;
  float acc[NB];
#pragma unroll
  for (int b = 0; b < NB; ++b) acc[b] = 0.f;
  __shared__ float sctx[NB][128];
  for (int k0 = 0; k0 < 2048; k0 += 128) {
    __syncthreads();
    for (int i = threadIdx.x; i < NB * 128; i += 256) {
      int bb = i >> 7, kk = i & 127;
      sctx[bb][kk] = ctx[(size_t)bb * 2048 + k0 + kk];
    }
    __syncthreads();
    for (int kk = 0; kk < 128; ++kk) {
      float wv = wp[(size_t)(k0 + kk) * NV + v];
#pragma unroll
      for (int b = 0; b < NB; ++b) acc[b] += sctx[b][kk] * wv;
    }
  }
#pragma unroll
  for (int b = 0; b < NB; ++b) out[(size_t)b * NV + v] = acc[b] + bp[v];
}

// ---------------- launch ----------------
extern "C" void kernel_launch(void* const* d_in, const int* in_sizes, int n_in,
                              void* d_out, int out_size, void* d_ws, size_t ws_size,
                              hipStream_t stream) {
  const int* x = (const int*)d_in[0];
  const float* emb = (const float*)d_in[1];
  const float* pos = (const float*)d_in[2];
  const float* conv_w = (const float*)d_in[3];
  const float* conv_b = (const float*)d_in[4];
  const float* wg1 = (const float*)d_in[5];
  const float* bg1 = (const float*)d_in[6];
  const float* wmv = (const float*)d_in[7];
  const float* bmv = (const float*)d_in[8];
  const float* wmg = (const float*)d_in[9];
  const float* bmg = (const float*)d_in[10];
  const float* wrg = (const float*)d_in[11];
  const float* brg = (const float*)d_in[12];
  const float* rms_w = (const float*)d_in[13];
  const float* wp = (const float*)d_in[14];
  const float* bp = (const float*)d_in[15];
  float* out = (float*)d_out;

  char* ws = (char*)d_ws;
  size_t off = 0;
  auto alloc = [&](size_t bytes) -> void* {
    void* p = ws + off;
    off += (bytes + 255) & ~(size_t)255;
    return p;
  };
  bf16_t* h0p = (bf16_t*)alloc((size_t)NB * SP * ND * 2);    // conv input, padded
  bf16_t* h = (bf16_t*)alloc((size_t)NB * NS * ND * 2);      // conv output
  bf16_t* nodes = (bf16_t*)alloc((size_t)NB * NS * ND * 2);  // gated nodes (row 2047 dup'd)
  bf16_t* tb0 = (bf16_t*)alloc((size_t)NB * 1024 * ND * 2);
  bf16_t* tb1 = (bf16_t*)alloc((size_t)NB * 1024 * ND * 2);
  bf16_t* convT = (bf16_t*)alloc((size_t)ND * 3072 * 2);
  bf16_t* wg1T = (bf16_t*)alloc((size_t)ND * 1024 * 2);
  bf16_t* wAllT = (bf16_t*)alloc((size_t)3072 * 2048 * 2);  // [wmv^T; wmg^T; wrg^T]
  float* bAll = (float*)alloc((size_t)3072 * 4);
  float* ctx = (float*)alloc((size_t)NB * 2048 * 4);
  if (off > ws_size) return;  // workspace too small: bail (will fail validation visibly)
  // fused tree-GEMM bf16 logits [MCHUNK][3072] = 201MB, aliases h0p+h (dead by tree time)
  bf16_t* fbuf = (bf16_t*)ws;

  dim3 t256(256), tb32(32, 8);

  // weight conversions (transpose to N x K bf16)
  conv_transpose_k<<<dim3(ND / 32, 3072 / 32), tb32, 0, stream>>>(conv_w, convT, 3072, ND);
  conv_transpose_k<<<dim3(ND / 32, ND / 32), tb32, 0, stream>>>(wg1, wg1T, ND, ND);
  conv_transpose_k<<<dim3(ND / 32, 2048 / 32), tb32, 0, stream>>>(wmv, wAllT, 2048, ND);
  conv_transpose_k<<<dim3(ND / 32, 2048 / 32), tb32, 0, stream>>>(wmg, wAllT + (size_t)1024 * 2048, 2048, ND);
  conv_transpose_k<<<dim3(ND / 32, 2048 / 32), tb32, 0, stream>>>(wrg, wAllT + (size_t)2048 * 2048, 2048, ND);
  concat3_k<<<12, t256, 0, stream>>>(bmv, bmg, brg, bAll);

  zero_pad_k<<<64, t256, 0, stream>>>(h0p);
  embed_k<<<NB * NS, t256, 0, stream>>>(x, emb, pos, h0p);

  // conv as GEMM over contiguous 3*D windows (row remap +2/batch): M=65536 N=1024 K=3072
  // grid 4x256: gpx=1, nxg=4 (1 panel/XCD, 1.5MB L2-resident), ych=128
  gemm256<0><<<1024, 512, 0, stream>>>(h0p, convT, conv_b, nullptr, h,
                                       NB * NS, ND, 3072, ND, 11, 2, 4, 1, 4, 128);
  // nodes = h * sigmoid(h@wg1 + bg1): M=65536 N=1024 K=1024
  gemm256<1><<<1024, 512, 0, stream>>>(h, wg1T, bg1, h, nodes,
                                       NB * NS, ND, ND, ND, 0, 0, 4, 1, 4, 128);
  dup_row_k<<<NB, t256, 0, stream>>>(nodes);  // pad odd level: row 2047 := row 2046

  const bf16_t* cur = nodes;
  bf16_t* bufs[2] = {tb0, tb1};
  int pp = 0;
  for (int L = NS; L > 1; L >>= 1) {
    int M = NB * (L / 2);
    for (int c = 0; c < M; c += MCHUNK) {
      int mc = M - c < MCHUNK ? M - c : MCHUNK;
      int GY = (mc + 255) / 256;
      if ((GY & 1) == 0)  // partition: 3 panels/XCD (4.5MB), A dup x4
        gemm256<3><<<12 * GY, 512, 0, stream>>>(cur + (size_t)c * 2048, wAllT, bAll, nullptr,
                                                fbuf, mc, 3072, 2048, 2048, 0, 0, 12, 3, 4, GY / 2);
      else                // small level: linear mapping
        gemm256<3><<<12 * GY, 512, 0, stream>>>(cur + (size_t)c * 2048, wAllT, bAll, nullptr,
                                                fbuf, mc, 3072, 2048, 2048, 0, 0, 12, 0, 0, 0);
      tree_combine_k<<<mc, t256, 0, stream>>>(fbuf, cur + (size_t)c * 2048, rms_w,
                                              bufs[pp] + (size_t)c * ND);
    }
    cur = bufs[pp];
    pp ^= 1;
  }

  build_ctx_k<<<NB, t256, 0, stream>>>(cur, nodes, ctx);
  final_proj_k<<<NV / 256, t256, 0, stream>>>(ctx, wp, bp, out);
}

// Round 6
// 2859.344 us; speedup vs baseline: 1.0801x; 1.0801x over previous
//
#include <hip/hip_runtime.h>
#include <stdint.h>

typedef __bf16 bf16_t;
typedef __attribute__((ext_vector_type(8))) __bf16 bf16x8;
typedef __attribute__((ext_vector_type(4))) __bf16 bf16x4;
typedef __attribute__((ext_vector_type(4))) float f32x4;

#define NB 32
#define NS 2048
#define ND 1024
#define NV 32000
#define SP 2050       // padded rows per batch for conv (1 zero row each side)

__device__ __forceinline__ float sigmoid_(float x) { return 1.0f / (1.0f + __expf(-x)); }

__device__ __forceinline__ void gload_lds16(const void* g, void* lds) {
  __builtin_amdgcn_global_load_lds((const __attribute__((address_space(1))) void*)g,
                                   (__attribute__((address_space(3))) void*)lds, 16, 0, 0);
}

// ---------------- prep / elementwise kernels ----------------

__global__ void zero_pad_k(bf16_t* h0p) {
  int i = blockIdx.x;  // 0..63 : 2 pad rows per batch
  int b = i >> 1;
  size_t row = (size_t)b * SP + ((i & 1) ? (SP - 1) : 0);
  bf16x4 z = {};
  *(bf16x4*)(h0p + row * ND + threadIdx.x * 4) = z;
}

__global__ void embed_k(const int* __restrict__ x, const float* __restrict__ emb,
                        const float* __restrict__ pos, bf16_t* __restrict__ h0p) {
  int bs = blockIdx.x;  // 0..NB*NS-1
  int b = bs >> 11, s = bs & (NS - 1);
  int idx = x[bs];
  const float* e = emb + (size_t)idx * ND;
  const float* p = pos + (size_t)s * ND;
  bf16_t* o = h0p + ((size_t)b * SP + s + 1) * ND;
  int d = threadIdx.x * 4;
  f32x4 ev = *(const f32x4*)(e + d);
  f32x4 pv = *(const f32x4*)(p + d);
  bf16x4 ov;
  ov[0] = (bf16_t)(ev[0] + pv[0]);
  ov[1] = (bf16_t)(ev[1] + pv[1]);
  ov[2] = (bf16_t)(ev[2] + pv[2]);
  ov[3] = (bf16_t)(ev[3] + pv[3]);
  *(bf16x4*)(o + d) = ov;
}

// f32 (R x C) -> bf16 (C x R) transpose+convert, 32x32 LDS tiles
__global__ void conv_transpose_k(const float* __restrict__ in, bf16_t* __restrict__ out,
                                 int R, int C) {
  __shared__ float tile[32][33];
  int tc = blockIdx.x * 32, tr = blockIdx.y * 32;
  int tx = threadIdx.x;
  for (int i = threadIdx.y; i < 32; i += 8)
    tile[i][tx] = in[(size_t)(tr + i) * C + tc + tx];
  __syncthreads();
  for (int i = threadIdx.y; i < 32; i += 8)
    out[(size_t)(tc + i) * R + tr + tx] = (bf16_t)tile[tx][i];
}

__global__ void dup_row_k(bf16_t* nodes) {
  int b = blockIdx.x;
  const bf16_t* src = nodes + ((size_t)b * NS + NS - 2) * ND;
  bf16_t* dst = nodes + ((size_t)b * NS + NS - 1) * ND;
  int d = threadIdx.x * 4;
  *(bf16x4*)(dst + d) = *(const bf16x4*)(src + d);
}

__global__ void concat3_k(const float* __restrict__ a, const float* __restrict__ b,
                          const float* __restrict__ c, float* __restrict__ o) {
  int i = blockIdx.x * 256 + threadIdx.x;  // 0..3071
  o[i] = i < 1024 ? a[i] : (i < 2048 ? b[i - 1024] : c[i - 2048]);
}

// ---------------- 256x256 8-phase GEMM: C = A(MxK, lda) @ Bt(NxK)^T + bias ----------
// BK=64, 512 threads = 8 waves (2M x 4N), per-wave C = 128x64, acc[8][4].
// LDS 128KB: sA/sB[2][256][64] bf16, XOR chunk swizzle; staged via pre-swizzled
// global source, linear dest. 4 phases per K-tile, counted vmcnt at boundary.
// EPI 0: bf16   1: bf16 aux*sigmoid(v) (GLU)   3: bf16 tree logits
template <int EPI>
__global__ __launch_bounds__(512, 2) void gemm256(
    const bf16_t* __restrict__ A, const bf16_t* __restrict__ Bt,
    const float* __restrict__ bias, const void* aux, void* Cout,
    int M, int N, int K, int lda, int batchShift, int batchPad,
    int GX, int gpx, int nxg, int ych) {
  const int tid = threadIdx.x;
  const int lane = tid & 63;
  const int wave = tid >> 6;
  int n0, m0;
  if (nxg == 0) {  // linear mapping for small grids
    n0 = (blockIdx.x % GX) * 256;
    m0 = (blockIdx.x / GX) * 256;
  } else {  // XCD-partition: xcd owns gpx N-panels + contiguous Y slice
    const int id = blockIdx.x;
    const int xcd = id & 7;
    const int jb = id >> 3;
    const int xg = xcd % nxg;
    const int ysub = xcd / nxg;
    n0 = (xg * gpx + (jb % gpx)) * 256;
    m0 = (ysub * ych + (jb / gpx)) * 256;
  }
  const int waveM = wave >> 2, waveN = wave & 3;

  __shared__ __align__(16) bf16_t sA[2][256 * 64];
  __shared__ __align__(16) bf16_t sB[2][256 * 64];

  f32x4 acc[8][4] = {};

  const int srow = tid >> 3;  // 0..63
  const int sj = tid & 7;
  const int wbase = wave * 8;

  auto stageA = [&](int buf, int kt, int half) {
#pragma unroll
    for (int r = 0; r < 2; ++r) {
      int lr = half * 128 + r * 64 + srow;  // tile row 0..255
      int sc = sj ^ (lr & 7);               // pre-swizzled source chunk
      int g = m0 + lr;
      if (g > M - 1) g = M - 1;
      size_t grow = (size_t)g + (size_t)(((unsigned)g) >> batchShift) * batchPad;
      gload_lds16(A + grow * (size_t)lda + (kt * 64 + sc * 8),
                  &sA[buf][(size_t)(half * 128 + r * 64 + wbase) * 64]);
    }
  };
  auto stageB = [&](int buf, int kt, int half) {
#pragma unroll
    for (int r = 0; r < 2; ++r) {
      int lr = half * 128 + r * 64 + srow;
      int sc = sj ^ (lr & 7);
      int g = n0 + lr;
      if (g > N - 1) g = N - 1;
      gload_lds16(Bt + (size_t)g * K + (kt * 64 + sc * 8),
                  &sB[buf][(size_t)(half * 128 + r * 64 + wbase) * 64]);
    }
  };

  const int nt = K >> 6;
  // prologue: A(0), B(0) -> buf0; B(1) -> buf1; wait A(0)+B(0) landed
  stageA(0, 0, 0); stageA(0, 0, 1);
  stageB(0, 0, 0); stageB(0, 0, 1);
  if (nt > 1) {
    stageB(1, 1, 0); stageB(1, 1, 1);
    asm volatile("s_waitcnt vmcnt(4)" ::: "memory");
  } else {
    asm volatile("s_waitcnt vmcnt(0)" ::: "memory");
  }
  __builtin_amdgcn_s_barrier();

  const int rlane = lane & 15;
  const int klane = lane >> 4;
  bf16x8 bfr[4][2];

  for (int t = 0; t < nt; ++t) {
    const int buf = t & 1;
    const bf16_t* sa = sA[buf];
    const bf16_t* sb = sB[buf];
#pragma unroll
    for (int p = 0; p < 4; ++p) {
      // ---- ds_read section ----
      if (p == 0) {
#pragma unroll
        for (int j = 0; j < 4; ++j)
#pragma unroll
          for (int ks = 0; ks < 2; ++ks) {
            int rb = waveN * 64 + j * 16 + rlane;
            int kc = ks * 4 + klane;
            bfr[j][ks] = *(const bf16x8*)&sb[rb * 64 + ((kc ^ (rb & 7)) * 8)];
          }
      }
      bf16x8 af[2][2];
#pragma unroll
      for (int ii = 0; ii < 2; ++ii)
#pragma unroll
        for (int ks = 0; ks < 2; ++ks) {
          int ra = waveM * 128 + p * 32 + ii * 16 + rlane;
          int kc = ks * 4 + klane;
          af[ii][ks] = *(const bf16x8*)&sa[ra * 64 + ((kc ^ (ra & 7)) * 8)];
        }
      // ---- stage section ----
      if (p == 0) {
        if (t + 1 < nt) { stageA(buf ^ 1, t + 1, 0); stageA(buf ^ 1, t + 1, 1); }
      } else if (p == 1) {
        if (t + 2 < nt) stageB(buf, t + 2, 0);
      } else if (p == 2) {
        if (t + 2 < nt) stageB(buf, t + 2, 1);
      }
      __builtin_amdgcn_s_barrier();
      // ---- MFMA cluster ----
      __builtin_amdgcn_s_setprio(1);
#pragma unroll
      for (int ks = 0; ks < 2; ++ks)
#pragma unroll
        for (int ii = 0; ii < 2; ++ii)
#pragma unroll
          for (int j = 0; j < 4; ++j)
            acc[p * 2 + ii][j] = __builtin_amdgcn_mfma_f32_16x16x32_bf16(
                af[ii][ks], bfr[j][ks], acc[p * 2 + ii][j], 0, 0, 0);
      __builtin_amdgcn_s_setprio(0);
      if (p < 3) {
        __builtin_amdgcn_s_barrier();
      } else {
        if (t + 2 < nt)
          asm volatile("s_waitcnt vmcnt(4)" ::: "memory");
        else
          asm volatile("s_waitcnt vmcnt(0)" ::: "memory");
        __builtin_amdgcn_s_barrier();
      }
    }
  }

  // ---- epilogue ----
  const int colBase = n0 + waveN * 64 + rlane;
#pragma unroll
  for (int i = 0; i < 8; ++i) {
    const int rowBase = m0 + waveM * 128 + i * 16 + klane * 4;
#pragma unroll
    for (int j = 0; j < 4; ++j) {
      const int col = colBase + j * 16;
      const float bv = bias[col];
#pragma unroll
      for (int r = 0; r < 4; ++r) {
        const int row = rowBase + r;
        if (row >= M) continue;
        float v = acc[i][j][r] + bv;
        size_t o = (size_t)row * N + col;
        if constexpr (EPI == 0) {
          ((bf16_t*)Cout)[o] = (bf16_t)v;
        } else if constexpr (EPI == 1) {
          float hh = (float)((const bf16_t*)aux)[o];
          ((bf16_t*)Cout)[o] = (bf16_t)(hh * sigmoid_(v));
        } else {
          ((bf16_t*)Cout)[o] = (bf16_t)(col < 1024 ? v : sigmoid_(v));
        }
      }
    }
  }
}

// ---------------- small-M tree GEMM: 128x128 tile, BK=64 dbuf, split-K ----------
// C(f32 logits, N=3072) = A(Mx2048) @ wAllT(3072x2048)^T [+ bias on slice 0]
// Grid: 24 * GY * SK linear. Each block does kLen = 2048/SK of K.
// ATOMIC: atomicAdd partial sums into pre-zeroed fbuf32; else direct store.
template <bool ATOMIC>
__global__ __launch_bounds__(256, 2) void gemm128s(
    const bf16_t* __restrict__ A, const bf16_t* __restrict__ Bt,
    const float* __restrict__ bias, float* __restrict__ Cout,
    int M, int kLen, int nxy) {
  const int tid = threadIdx.x;
  const int lane = tid & 63;
  const int wave = tid >> 6;
  const int id = blockIdx.x;
  const int sk = id / nxy;
  const int rb2 = id % nxy;
  const int n0 = (rb2 % 24) * 128;
  const int m0 = (rb2 / 24) * 128;
  const int kOff = sk * kLen;

  const int waveM = wave >> 1, waveN = wave & 1;

  __shared__ __align__(16) bf16_t sA[2][128 * 64];
  __shared__ __align__(16) bf16_t sB[2][128 * 64];

  f32x4 acc[4][4] = {};

  const int srow = wave * 8 + (lane >> 3);  // + j*32 = tile row staged by this lane
  const int sj = lane & 7;                  // LDS chunk column within row

  auto stage = [&](int buf, int kk0) {
#pragma unroll
    for (int j = 0; j < 4; ++j) {
      int rowT = j * 32 + srow;
      int k8 = sj ^ (rowT & 7);  // pre-swizzled source chunk
      int gm = m0 + rowT;
      if (gm > M - 1) gm = M - 1;
      gload_lds16(A + (size_t)gm * 2048 + (kk0 + k8 * 8), &sA[buf][(j * 256 + wave * 64) * 8]);
      int gn = n0 + rowT;
      gload_lds16(Bt + (size_t)gn * 2048 + (kk0 + k8 * 8), &sB[buf][(j * 256 + wave * 64) * 8]);
    }
  };

  stage(0, kOff);
  __syncthreads();

  const int nt = kLen >> 6;
  int cur = 0;
  const int ar = waveM * 64 + (lane & 15);
  const int br = waveN * 64 + (lane & 15);
  const int kb0 = lane >> 4;

  for (int t = 0; t < nt; ++t) {
    if (t + 1 < nt) stage(cur ^ 1, kOff + (t + 1) * 64);

    const bf16_t* sa = sA[cur];
    const bf16_t* sb = sB[cur];
    bf16x8 af[2][4], bfr[2][4];
#pragma unroll
    for (int ks = 0; ks < 2; ++ks) {
      int kb = kb0 + ks * 4;
#pragma unroll
      for (int i = 0; i < 4; ++i) {
        int ra = ar + i * 16;
        af[ks][i] = *(const bf16x8*)&sa[ra * 64 + ((kb ^ (ra & 7)) * 8)];
        int rbq = br + i * 16;
        bfr[ks][i] = *(const bf16x8*)&sb[rbq * 64 + ((kb ^ (rbq & 7)) * 8)];
      }
    }
#pragma unroll
    for (int ks = 0; ks < 2; ++ks)
#pragma unroll
      for (int i = 0; i < 4; ++i)
#pragma unroll
        for (int j = 0; j < 4; ++j)
          acc[i][j] = __builtin_amdgcn_mfma_f32_16x16x32_bf16(af[ks][i], bfr[ks][j], acc[i][j], 0, 0, 0);
    __syncthreads();
    cur ^= 1;
  }

  const int colBase = n0 + waveN * 64 + (lane & 15);
#pragma unroll
  for (int i = 0; i < 4; ++i) {
    const int rowBase = m0 + waveM * 64 + i * 16 + (lane >> 4) * 4;
#pragma unroll
    for (int jj = 0; jj < 4; ++jj) {
      const int col = colBase + jj * 16;
      const float bv = (!ATOMIC || kOff == 0) ? bias[col] : 0.0f;
#pragma unroll
      for (int r = 0; r < 4; ++r) {
        const int row = rowBase + r;
        if (row >= M) continue;
        float v = acc[i][jj][r] + bv;
        size_t o = (size_t)row * 3072 + col;
        if constexpr (ATOMIC)
          atomicAdd(&Cout[o], v);
        else
          Cout[o] = v;
      }
    }
  }
}

// ---------------- tree combine (bf16 logits path, gemm256): ----------------
// fb row: [0,1024) = val, [1024,2048) = sigmoid(mg), [2048,3072) = sigmoid(rg)
__global__ __launch_bounds__(256) void tree_combine_k(
    const bf16_t* __restrict__ fb, const bf16_t* __restrict__ cur,
    const float* __restrict__ rms_w, bf16_t* __restrict__ outb) {
  const int m = blockIdx.x;
  const int t = threadIdx.x;
  const int d = t * 4;
  const bf16_t* row = fb + (size_t)m * 3072;
  bf16x4 vb = *(const bf16x4*)(row + d);
  bf16x4 gb = *(const bf16x4*)(row + 1024 + d);
  bf16x4 rb = *(const bf16x4*)(row + 2048 + d);
  f32x4 vg;
#pragma unroll
  for (int k = 0; k < 4; ++k) vg[k] = (float)vb[k] * (float)gb[k];
  float ss = vg[0] * vg[0] + vg[1] * vg[1] + vg[2] * vg[2] + vg[3] * vg[3];
#pragma unroll
  for (int o = 32; o > 0; o >>= 1) ss += __shfl_xor(ss, o);
  __shared__ float red[4];
  if ((t & 63) == 0) red[t >> 6] = ss;
  __syncthreads();
  float ms = (red[0] + red[1] + red[2] + red[3]) * (1.0f / ND);
  float scale = rsqrtf(ms + 1.1920929e-07f);
  f32x4 w = *(const f32x4*)(rms_w + d);
  const bf16_t* c0 = cur + (size_t)m * 2048;
  bf16x4 lv = *(const bf16x4*)(c0 + d);
  bf16x4 rv = *(const bf16x4*)(c0 + ND + d);
  bf16x4 o4;
#pragma unroll
  for (int k = 0; k < 4; ++k) {
    float merged = vg[k] * scale * w[k];
    float resid = 0.5f * ((float)lv[k] + (float)rv[k]);
    float g = (float)rb[k];
    o4[k] = (bf16_t)(g * merged + (1.0f - g) * resid);
  }
  *(bf16x4*)(outb + (size_t)m * ND + d) = o4;
}

// ---------------- tree combine (f32 raw logits path, gemm128s): ----------------
// fb row: [0,1024) = val logit, [1024,2048) = mg logit, [2048,3072) = rg logit
__global__ __launch_bounds__(256) void tree_combine32_k(
    const float* __restrict__ fb, const bf16_t* __restrict__ cur,
    const float* __restrict__ rms_w, bf16_t* __restrict__ outb) {
  const int m = blockIdx.x;
  const int t = threadIdx.x;
  const int d = t * 4;
  const float* row = fb + (size_t)m * 3072;
  f32x4 v = *(const f32x4*)(row + d);
  f32x4 gl = *(const f32x4*)(row + 1024 + d);
  f32x4 rl = *(const f32x4*)(row + 2048 + d);
  f32x4 vg;
#pragma unroll
  for (int k = 0; k < 4; ++k) vg[k] = v[k] * sigmoid_(gl[k]);
  float ss = vg[0] * vg[0] + vg[1] * vg[1] + vg[2] * vg[2] + vg[3] * vg[3];
#pragma unroll
  for (int o = 32; o > 0; o >>= 1) ss += __shfl_xor(ss, o);
  __shared__ float red[4];
  if ((t & 63) == 0) red[t >> 6] = ss;
  __syncthreads();
  float ms = (red[0] + red[1] + red[2] + red[3]) * (1.0f / ND);
  float scale = rsqrtf(ms + 1.1920929e-07f);
  f32x4 w = *(const f32x4*)(rms_w + d);
  const bf16_t* c0 = cur + (size_t)m * 2048;
  bf16x4 lv = *(const bf16x4*)(c0 + d);
  bf16x4 rv = *(const bf16x4*)(c0 + ND + d);
  bf16x4 o4;
#pragma unroll
  for (int k = 0; k < 4; ++k) {
    float merged = vg[k] * scale * w[k];
    float resid = 0.5f * ((float)lv[k] + (float)rv[k]);
    float g = sigmoid_(rl[k]);
    o4[k] = (bf16_t)(g * merged + (1.0f - g) * resid);
  }
  *(bf16x4*)(outb + (size_t)m * ND + d) = o4;
}

__global__ void build_ctx_k(const bf16_t* __restrict__ root, const bf16_t* __restrict__ nodes,
                            float* __restrict__ ctx) {
  int b = blockIdx.x, t = threadIdx.x;
  const bf16_t* r = root + (size_t)b * ND;
  const bf16_t* l = nodes + ((size_t)b * NS + NS - 2) * ND;
  int d = t * 4;
#pragma unroll
  for (int k = 0; k < 4; ++k) {
    ctx[(size_t)b * 2048 + d + k] = (float)r[d + k];
    ctx[(size_t)b * 2048 + ND + d + k] = (float)l[d + k];
  }
}

// ---------------- final projection in f32: out[b,v] = ctx[b,:]@wp[:,v] + bp[v] ----------------
__global__ __launch_bounds__(256) void final_proj_k(
    const float* __restrict__ ctx, const float* __restrict__ wp,
    const float* __restrict__ bp, float* __restrict__ out) {
  const int v = blockIdx.x * 256 + threadIdx.x;
  float acc[NB];
#pragma unroll
  for (int b = 0; b < NB; ++b) acc[b] = 0.f;
  __shared__ float sctx[NB][128];
  for (int k0 = 0; k0 < 2048; k0 += 128) {
    __syncthreads();
    for (int i = threadIdx.x; i < NB * 128; i += 256) {
      int bb = i >> 7, kk = i & 127;
      sctx[bb][kk] = ctx[(size_t)bb * 2048 + k0 + kk];
    }
    __syncthreads();
    for (int kk = 0; kk < 128; ++kk) {
      float wv = wp[(size_t)(k0 + kk) * NV + v];
#pragma unroll
      for (int b = 0; b < NB; ++b) acc[b] += sctx[b][kk] * wv;
    }
  }
#pragma unroll
  for (int b = 0; b < NB; ++b) out[(size_t)b * NV + v] = acc[b] + bp[v];
}

// ---------------- launch ----------------
extern "C" void kernel_launch(void* const* d_in, const int* in_sizes, int n_in,
                              void* d_out, int out_size, void* d_ws, size_t ws_size,
                              hipStream_t stream) {
  const int* x = (const int*)d_in[0];
  const float* emb = (const float*)d_in[1];
  const float* pos = (const float*)d_in[2];
  const float* conv_w = (const float*)d_in[3];
  const float* conv_b = (const float*)d_in[4];
  const float* wg1 = (const float*)d_in[5];
  const float* bg1 = (const float*)d_in[6];
  const float* wmv = (const float*)d_in[7];
  const float* bmv = (const float*)d_in[8];
  const float* wmg = (const float*)d_in[9];
  const float* bmg = (const float*)d_in[10];
  const float* wrg = (const float*)d_in[11];
  const float* brg = (const float*)d_in[12];
  const float* rms_w = (const float*)d_in[13];
  const float* wp = (const float*)d_in[14];
  const float* bp = (const float*)d_in[15];
  float* out = (float*)d_out;

  char* ws = (char*)d_ws;
  size_t off = 0;
  auto alloc = [&](size_t bytes) -> void* {
    void* p = ws + off;
    off += (bytes + 255) & ~(size_t)255;
    return p;
  };
  bf16_t* h0p = (bf16_t*)alloc((size_t)NB * SP * ND * 2);    // conv input, padded
  bf16_t* h = (bf16_t*)alloc((size_t)NB * NS * ND * 2);      // conv output
  bf16_t* nodes = (bf16_t*)alloc((size_t)NB * NS * ND * 2);  // gated nodes (row 2047 dup'd)
  bf16_t* tb0 = (bf16_t*)alloc((size_t)NB * 1024 * ND * 2);
  bf16_t* tb1 = (bf16_t*)alloc((size_t)NB * 1024 * ND * 2);
  bf16_t* convT = (bf16_t*)alloc((size_t)ND * 3072 * 2);
  bf16_t* wg1T = (bf16_t*)alloc((size_t)ND * 1024 * 2);
  bf16_t* wAllT = (bf16_t*)alloc((size_t)3072 * 2048 * 2);  // [wmv^T; wmg^T; wrg^T]
  float* bAll = (float*)alloc((size_t)3072 * 4);
  float* ctx = (float*)alloc((size_t)NB * 2048 * 4);
  if (off > ws_size) return;  // workspace too small: bail (will fail validation visibly)
  // tree logits alias dead conv buffers: bf16 [32768][3072] = 201MB (gemm256 path)
  // or f32 [<=8192][3072] = 100MB (gemm128s path); h0p+h region = 268MB.
  bf16_t* fbuf = (bf16_t*)ws;
  float* fbuf32 = (float*)ws;

  dim3 t256(256), tb32(32, 8);

  // weight conversions (transpose to N x K bf16)
  conv_transpose_k<<<dim3(ND / 32, 3072 / 32), tb32, 0, stream>>>(conv_w, convT, 3072, ND);
  conv_transpose_k<<<dim3(ND / 32, ND / 32), tb32, 0, stream>>>(wg1, wg1T, ND, ND);
  conv_transpose_k<<<dim3(ND / 32, 2048 / 32), tb32, 0, stream>>>(wmv, wAllT, 2048, ND);
  conv_transpose_k<<<dim3(ND / 32, 2048 / 32), tb32, 0, stream>>>(wmg, wAllT + (size_t)1024 * 2048, 2048, ND);
  conv_transpose_k<<<dim3(ND / 32, 2048 / 32), tb32, 0, stream>>>(wrg, wAllT + (size_t)2048 * 2048, 2048, ND);
  concat3_k<<<12, t256, 0, stream>>>(bmv, bmg, brg, bAll);

  zero_pad_k<<<64, t256, 0, stream>>>(h0p);
  embed_k<<<NB * NS, t256, 0, stream>>>(x, emb, pos, h0p);

  // conv as GEMM over contiguous 3*D windows (row remap +2/batch): M=65536 N=1024 K=3072
  gemm256<0><<<1024, 512, 0, stream>>>(h0p, convT, conv_b, nullptr, h,
                                       NB * NS, ND, 3072, ND, 11, 2, 4, 1, 4, 128);
  // nodes = h * sigmoid(h@wg1 + bg1): M=65536 N=1024 K=1024
  gemm256<1><<<1024, 512, 0, stream>>>(h, wg1T, bg1, h, nodes,
                                       NB * NS, ND, ND, ND, 0, 0, 4, 1, 4, 128);
  dup_row_k<<<NB, t256, 0, stream>>>(nodes);  // pad odd level: row 2047 := row 2046

  const bf16_t* cur = nodes;
  bf16_t* bufs[2] = {tb0, tb1};
  int pp = 0;
  for (int L = NS; L > 1; L >>= 1) {
    int M = NB * (L / 2);
    if (M >= 16384) {
      // big level: 256^2 8-phase, bf16 fused logits
      int GY = M / 256;  // 128 or 64 (even)
      gemm256<3><<<12 * GY, 512, 0, stream>>>(cur, wAllT, bAll, nullptr, fbuf,
                                              M, 3072, 2048, 2048, 0, 0, 12, 3, 4, GY / 2);
      tree_combine_k<<<M, t256, 0, stream>>>(fbuf, cur, rms_w, bufs[pp]);
    } else {
      // small level: 128^2 split-K, f32 logits
      int GY = (M + 127) / 128;
      int nxy = 24 * GY;
      int SK = 1;
      while (nxy * SK < 768 && SK < 16) SK <<= 1;
      if (SK > 1) {
        hipMemsetAsync(fbuf32, 0, (size_t)M * 3072 * 4, stream);
        gemm128s<true><<<nxy * SK, t256, 0, stream>>>(cur, wAllT, bAll, fbuf32,
                                                      M, 2048 / SK, nxy);
      } else {
        gemm128s<false><<<nxy, t256, 0, stream>>>(cur, wAllT, bAll, fbuf32, M, 2048, nxy);
      }
      tree_combine32_k<<<M, t256, 0, stream>>>(fbuf32, cur, rms_w, bufs[pp]);
    }
    cur = bufs[pp];
    pp ^= 1;
  }

  build_ctx_k<<<NB, t256, 0, stream>>>(cur, nodes, ctx);
  final_proj_k<<<NV / 256, t256, 0, stream>>>(ctx, wp, bp, out);
}

// Round 7
// 2819.134 us; speedup vs baseline: 1.0956x; 1.0143x over previous
//
#include <hip/hip_runtime.h>
#include <stdint.h>

typedef __bf16 bf16_t;
typedef __attribute__((ext_vector_type(8))) __bf16 bf16x8;
typedef __attribute__((ext_vector_type(4))) __bf16 bf16x4;
typedef __attribute__((ext_vector_type(4))) float f32x4;

#define NB 32
#define NS 2048
#define ND 1024
#define NV 32000
#define SP 2050       // padded rows per batch for conv (1 zero row each side)

__device__ __forceinline__ float sigmoid_(float x) { return 1.0f / (1.0f + __expf(-x)); }

__device__ __forceinline__ void gload_lds16(const void* g, void* lds) {
  __builtin_amdgcn_global_load_lds((const __attribute__((address_space(1))) void*)g,
                                   (__attribute__((address_space(3))) void*)lds, 16, 0, 0);
}

// ---------------- prep / elementwise kernels ----------------

__global__ void zero_pad_k(bf16_t* h0p) {
  int i = blockIdx.x;  // 0..63 : 2 pad rows per batch
  int b = i >> 1;
  size_t row = (size_t)b * SP + ((i & 1) ? (SP - 1) : 0);
  bf16x4 z = {};
  *(bf16x4*)(h0p + row * ND + threadIdx.x * 4) = z;
}

__global__ void embed_k(const int* __restrict__ x, const float* __restrict__ emb,
                        const float* __restrict__ pos, bf16_t* __restrict__ h0p) {
  int bs = blockIdx.x;  // 0..NB*NS-1
  int b = bs >> 11, s = bs & (NS - 1);
  int idx = x[bs];
  const float* e = emb + (size_t)idx * ND;
  const float* p = pos + (size_t)s * ND;
  bf16_t* o = h0p + ((size_t)b * SP + s + 1) * ND;
  int d = threadIdx.x * 4;
  f32x4 ev = *(const f32x4*)(e + d);
  f32x4 pv = *(const f32x4*)(p + d);
  bf16x4 ov;
  ov[0] = (bf16_t)(ev[0] + pv[0]);
  ov[1] = (bf16_t)(ev[1] + pv[1]);
  ov[2] = (bf16_t)(ev[2] + pv[2]);
  ov[3] = (bf16_t)(ev[3] + pv[3]);
  *(bf16x4*)(o + d) = ov;
}

// f32 (R x C) -> bf16 (C x R) transpose+convert, 32x32 LDS tiles
__global__ void conv_transpose_k(const float* __restrict__ in, bf16_t* __restrict__ out,
                                 int R, int C) {
  __shared__ float tile[32][33];
  int tc = blockIdx.x * 32, tr = blockIdx.y * 32;
  int tx = threadIdx.x;
  for (int i = threadIdx.y; i < 32; i += 8)
    tile[i][tx] = in[(size_t)(tr + i) * C + tc + tx];
  __syncthreads();
  for (int i = threadIdx.y; i < 32; i += 8)
    out[(size_t)(tc + i) * R + tr + tx] = (bf16_t)tile[tx][i];
}

__global__ void dup_row_k(bf16_t* nodes) {
  int b = blockIdx.x;
  const bf16_t* src = nodes + ((size_t)b * NS + NS - 2) * ND;
  bf16_t* dst = nodes + ((size_t)b * NS + NS - 1) * ND;
  int d = threadIdx.x * 4;
  *(bf16x4*)(dst + d) = *(const bf16x4*)(src + d);
}

__global__ void concat3_k(const float* __restrict__ a, const float* __restrict__ b,
                          const float* __restrict__ c, float* __restrict__ o) {
  int i = blockIdx.x * 256 + threadIdx.x;  // 0..3071
  o[i] = i < 1024 ? a[i] : (i < 2048 ? b[i - 1024] : c[i - 2048]);
}

// ---------------- 256x256 GEMM, BK=32, 4-ring LDS, 1 barrier/K-tile ----------
// 512 threads = 8 waves (2M x 4N), per-wave C = 128x64, acc[8][4].
// LDS 128KB: sA/sB[4][256][32] bf16 ring. Stage for tile t+3 issued at tile t
// (ring (t+3)%4; WAR: last read at t-1, >=1 barrier apart). Boundary: counted
// s_waitcnt vmcnt(8) retires tile-(t+1)'s 4 loads (RAW), leaves 8 in flight;
// per-wave vmcnt precedes s_barrier so all waves' stages are visible.
// No lgkm drains: compiler's incremental lgkmcnt overlaps ds_reads with MFMA.
// XOR chunk swizzle: stored chunk c holds logical chunk c ^ (row&3), staged via
// pre-swizzled global source (linear LDS dest). Requires K % 128 == 0.
// EPI 0: bf16   1: bf16 aux*sigmoid(v) (GLU)   3: bf16 tree logits
template <int EPI>
__global__ __launch_bounds__(512, 2) void gemm256(
    const bf16_t* __restrict__ A, const bf16_t* __restrict__ Bt,
    const float* __restrict__ bias, const void* aux, void* Cout,
    int M, int N, int K, int lda, int batchShift, int batchPad,
    int GX, int gpx, int nxg, int ych) {
  const int tid = threadIdx.x;
  const int lane = tid & 63;
  const int wave = tid >> 6;
  int n0, m0;
  if (nxg == 0) {  // linear mapping for small grids
    n0 = (blockIdx.x % GX) * 256;
    m0 = (blockIdx.x / GX) * 256;
  } else {  // XCD-partition: xcd owns gpx N-panels + contiguous Y slice
    const int id = blockIdx.x;
    const int xcd = id & 7;
    const int jb = id >> 3;
    const int xg = xcd % nxg;
    const int ysub = xcd / nxg;
    n0 = (xg * gpx + (jb % gpx)) * 256;
    m0 = (ysub * ych + (jb / gpx)) * 256;
  }
  const int waveM = wave >> 2, waveN = wave & 3;

  __shared__ __align__(16) bf16_t sA[4][256 * 32];
  __shared__ __align__(16) bf16_t sB[4][256 * 32];

  f32x4 acc[8][4] = {};

  const int srow = tid >> 2;  // 0..127
  const int sj = tid & 3;     // 16B chunk within 64B row
  const int wb16 = wave * 16;

  auto stage = [&](int ring, int kt) {  // 4 gload instr: A+B full tile rows
#pragma unroll
    for (int r = 0; r < 2; ++r) {
      int rowT = r * 128 + srow;
      int sc = sj ^ (rowT & 3);  // pre-swizzled source chunk
      int gm = m0 + rowT;
      if (gm > M - 1) gm = M - 1;
      size_t grow = (size_t)gm + (size_t)(((unsigned)gm) >> batchShift) * batchPad;
      gload_lds16(A + grow * (size_t)lda + (kt * 32 + sc * 8),
                  &sA[ring][(size_t)(r * 128 + wb16) * 32]);
      int gn = n0 + rowT;
      if (gn > N - 1) gn = N - 1;
      gload_lds16(Bt + (size_t)gn * K + (kt * 32 + sc * 8),
                  &sB[ring][(size_t)(r * 128 + wb16) * 32]);
    }
  };

  const int nt = K >> 5;  // BK=32; nt % 4 == 0, nt >= 4
  stage(0, 0);
  stage(1, 1);
  stage(2, 2);
  asm volatile("s_waitcnt vmcnt(8)" ::: "memory");  // tile 0 landed (per wave)
  __builtin_amdgcn_s_barrier();
  __builtin_amdgcn_sched_barrier(0);

  const int rlane = lane & 15;
  const int klane = lane >> 4;

  for (int t0 = 0; t0 < nt; t0 += 4) {
#pragma unroll
    for (int u = 0; u < 4; ++u) {
      const int t = t0 + u;
      if (t + 3 < nt) stage((u + 3) & 3, t + 3);
      const bf16_t* sa = sA[u];
      const bf16_t* sb = sB[u];
      bf16x8 af[8], bfr[4];
#pragma unroll
      for (int j = 0; j < 4; ++j) {
        int rb = waveN * 64 + j * 16 + rlane;
        bfr[j] = *(const bf16x8*)&sb[rb * 32 + ((klane ^ (rb & 3)) * 8)];
      }
#pragma unroll
      for (int i = 0; i < 8; ++i) {
        int ra = waveM * 128 + i * 16 + rlane;
        af[i] = *(const bf16x8*)&sa[ra * 32 + ((klane ^ (ra & 3)) * 8)];
      }
      __builtin_amdgcn_s_setprio(1);
#pragma unroll
      for (int i = 0; i < 8; ++i)
#pragma unroll
        for (int j = 0; j < 4; ++j)
          acc[i][j] = __builtin_amdgcn_mfma_f32_16x16x32_bf16(af[i], bfr[j], acc[i][j], 0, 0, 0);
      __builtin_amdgcn_s_setprio(0);
      if (t + 3 < nt)
        asm volatile("s_waitcnt vmcnt(8)" ::: "memory");
      else
        asm volatile("s_waitcnt vmcnt(0)" ::: "memory");
      __builtin_amdgcn_s_barrier();
      __builtin_amdgcn_sched_barrier(0);
    }
  }

  // ---- epilogue ----
  const int colBase = n0 + waveN * 64 + rlane;
#pragma unroll
  for (int i = 0; i < 8; ++i) {
    const int rowBase = m0 + waveM * 128 + i * 16 + klane * 4;
#pragma unroll
    for (int j = 0; j < 4; ++j) {
      const int col = colBase + j * 16;
      const float bv = bias[col];
#pragma unroll
      for (int r = 0; r < 4; ++r) {
        const int row = rowBase + r;
        if (row >= M) continue;
        float v = acc[i][j][r] + bv;
        size_t o = (size_t)row * N + col;
        if constexpr (EPI == 0) {
          ((bf16_t*)Cout)[o] = (bf16_t)v;
        } else if constexpr (EPI == 1) {
          float hh = (float)((const bf16_t*)aux)[o];
          ((bf16_t*)Cout)[o] = (bf16_t)(hh * sigmoid_(v));
        } else {
          ((bf16_t*)Cout)[o] = (bf16_t)(col < 1024 ? v : sigmoid_(v));
        }
      }
    }
  }
}

// ---------------- small-M tree GEMM: 128x128 tile, BK=64 dbuf, split-K ----------
// C(f32 logits, N=3072) = A(Mx2048) @ wAllT(3072x2048)^T [+ bias on slice 0]
// Grid: 24 * GY * SK linear. Each block does kLen = 2048/SK of K.
// ATOMIC: atomicAdd partial sums into pre-zeroed fbuf32; else direct store.
template <bool ATOMIC>
__global__ __launch_bounds__(256, 2) void gemm128s(
    const bf16_t* __restrict__ A, const bf16_t* __restrict__ Bt,
    const float* __restrict__ bias, float* __restrict__ Cout,
    int M, int kLen, int nxy) {
  const int tid = threadIdx.x;
  const int lane = tid & 63;
  const int wave = tid >> 6;
  const int id = blockIdx.x;
  const int sk = id / nxy;
  const int rb2 = id % nxy;
  const int n0 = (rb2 % 24) * 128;
  const int m0 = (rb2 / 24) * 128;
  const int kOff = sk * kLen;

  const int waveM = wave >> 1, waveN = wave & 1;

  __shared__ __align__(16) bf16_t sA[2][128 * 64];
  __shared__ __align__(16) bf16_t sB[2][128 * 64];

  f32x4 acc[4][4] = {};

  const int srow = wave * 8 + (lane >> 3);  // + j*32 = tile row staged by this lane
  const int sj = lane & 7;                  // LDS chunk column within row

  auto stage = [&](int buf, int kk0) {
#pragma unroll
    for (int j = 0; j < 4; ++j) {
      int rowT = j * 32 + srow;
      int k8 = sj ^ (rowT & 7);  // pre-swizzled source chunk
      int gm = m0 + rowT;
      if (gm > M - 1) gm = M - 1;
      gload_lds16(A + (size_t)gm * 2048 + (kk0 + k8 * 8), &sA[buf][(j * 256 + wave * 64) * 8]);
      int gn = n0 + rowT;
      gload_lds16(Bt + (size_t)gn * 2048 + (kk0 + k8 * 8), &sB[buf][(j * 256 + wave * 64) * 8]);
    }
  };

  stage(0, kOff);
  __syncthreads();

  const int nt = kLen >> 6;
  int cur = 0;
  const int ar = waveM * 64 + (lane & 15);
  const int br = waveN * 64 + (lane & 15);
  const int kb0 = lane >> 4;

  for (int t = 0; t < nt; ++t) {
    if (t + 1 < nt) stage(cur ^ 1, kOff + (t + 1) * 64);

    const bf16_t* sa = sA[cur];
    const bf16_t* sb = sB[cur];
    bf16x8 af[2][4], bfr[2][4];
#pragma unroll
    for (int ks = 0; ks < 2; ++ks) {
      int kb = kb0 + ks * 4;
#pragma unroll
      for (int i = 0; i < 4; ++i) {
        int ra = ar + i * 16;
        af[ks][i] = *(const bf16x8*)&sa[ra * 64 + ((kb ^ (ra & 7)) * 8)];
        int rbq = br + i * 16;
        bfr[ks][i] = *(const bf16x8*)&sb[rbq * 64 + ((kb ^ (rbq & 7)) * 8)];
      }
    }
#pragma unroll
    for (int ks = 0; ks < 2; ++ks)
#pragma unroll
      for (int i = 0; i < 4; ++i)
#pragma unroll
        for (int j = 0; j < 4; ++j)
          acc[i][j] = __builtin_amdgcn_mfma_f32_16x16x32_bf16(af[ks][i], bfr[ks][j], acc[i][j], 0, 0, 0);
    __syncthreads();
    cur ^= 1;
  }

  const int colBase = n0 + waveN * 64 + (lane & 15);
#pragma unroll
  for (int i = 0; i < 4; ++i) {
    const int rowBase = m0 + waveM * 64 + i * 16 + (lane >> 4) * 4;
#pragma unroll
    for (int jj = 0; jj < 4; ++jj) {
      const int col = colBase + jj * 16;
      const float bv = (!ATOMIC || kOff == 0) ? bias[col] : 0.0f;
#pragma unroll
      for (int r = 0; r < 4; ++r) {
        const int row = rowBase + r;
        if (row >= M) continue;
        float v = acc[i][jj][r] + bv;
        size_t o = (size_t)row * 3072 + col;
        if constexpr (ATOMIC)
          atomicAdd(&Cout[o], v);
        else
          Cout[o] = v;
      }
    }
  }
}

// ---------------- tree combine (bf16 logits path, gemm256): ----------------
// fb row: [0,1024) = val, [1024,2048) = sigmoid(mg), [2048,3072) = sigmoid(rg)
__global__ __launch_bounds__(256) void tree_combine_k(
    const bf16_t* __restrict__ fb, const bf16_t* __restrict__ cur,
    const float* __restrict__ rms_w, bf16_t* __restrict__ outb) {
  const int m = blockIdx.x;
  const int t = threadIdx.x;
  const int d = t * 4;
  const bf16_t* row = fb + (size_t)m * 3072;
  bf16x4 vb = *(const bf16x4*)(row + d);
  bf16x4 gb = *(const bf16x4*)(row + 1024 + d);
  bf16x4 rb = *(const bf16x4*)(row + 2048 + d);
  f32x4 vg;
#pragma unroll
  for (int k = 0; k < 4; ++k) vg[k] = (float)vb[k] * (float)gb[k];
  float ss = vg[0] * vg[0] + vg[1] * vg[1] + vg[2] * vg[2] + vg[3] * vg[3];
#pragma unroll
  for (int o = 32; o > 0; o >>= 1) ss += __shfl_xor(ss, o);
  __shared__ float red[4];
  if ((t & 63) == 0) red[t >> 6] = ss;
  __syncthreads();
  float ms = (red[0] + red[1] + red[2] + red[3]) * (1.0f / ND);
  float scale = rsqrtf(ms + 1.1920929e-07f);
  f32x4 w = *(const f32x4*)(rms_w + d);
  const bf16_t* c0 = cur + (size_t)m * 2048;
  bf16x4 lv = *(const bf16x4*)(c0 + d);
  bf16x4 rv = *(const bf16x4*)(c0 + ND + d);
  bf16x4 o4;
#pragma unroll
  for (int k = 0; k < 4; ++k) {
    float merged = vg[k] * scale * w[k];
    float resid = 0.5f * ((float)lv[k] + (float)rv[k]);
    float g = (float)rb[k];
    o4[k] = (bf16_t)(g * merged + (1.0f - g) * resid);
  }
  *(bf16x4*)(outb + (size_t)m * ND + d) = o4;
}

// ---------------- tree combine (f32 raw logits path, gemm128s): ----------------
// fb row: [0,1024) = val logit, [1024,2048) = mg logit, [2048,3072) = rg logit
__global__ __launch_bounds__(256) void tree_combine32_k(
    const float* __restrict__ fb, const bf16_t* __restrict__ cur,
    const float* __restrict__ rms_w, bf16_t* __restrict__ outb) {
  const int m = blockIdx.x;
  const int t = threadIdx.x;
  const int d = t * 4;
  const float* row = fb + (size_t)m * 3072;
  f32x4 v = *(const f32x4*)(row + d);
  f32x4 gl = *(const f32x4*)(row + 1024 + d);
  f32x4 rl = *(const f32x4*)(row + 2048 + d);
  f32x4 vg;
#pragma unroll
  for (int k = 0; k < 4; ++k) vg[k] = v[k] * sigmoid_(gl[k]);
  float ss = vg[0] * vg[0] + vg[1] * vg[1] + vg[2] * vg[2] + vg[3] * vg[3];
#pragma unroll
  for (int o = 32; o > 0; o >>= 1) ss += __shfl_xor(ss, o);
  __shared__ float red[4];
  if ((t & 63) == 0) red[t >> 6] = ss;
  __syncthreads();
  float ms = (red[0] + red[1] + red[2] + red[3]) * (1.0f / ND);
  float scale = rsqrtf(ms + 1.1920929e-07f);
  f32x4 w = *(const f32x4*)(rms_w + d);
  const bf16_t* c0 = cur + (size_t)m * 2048;
  bf16x4 lv = *(const bf16x4*)(c0 + d);
  bf16x4 rv = *(const bf16x4*)(c0 + ND + d);
  bf16x4 o4;
#pragma unroll
  for (int k = 0; k < 4; ++k) {
    float merged = vg[k] * scale * w[k];
    float resid = 0.5f * ((float)lv[k] + (float)rv[k]);
    float g = sigmoid_(rl[k]);
    o4[k] = (bf16_t)(g * merged + (1.0f - g) * resid);
  }
  *(bf16x4*)(outb + (size_t)m * ND + d) = o4;
}

__global__ void build_ctx_k(const bf16_t* __restrict__ root, const bf16_t* __restrict__ nodes,
                            float* __restrict__ ctx) {
  int b = blockIdx.x, t = threadIdx.x;
  const bf16_t* r = root + (size_t)b * ND;
  const bf16_t* l = nodes + ((size_t)b * NS + NS - 2) * ND;
  int d = t * 4;
#pragma unroll
  for (int k = 0; k < 4; ++k) {
    ctx[(size_t)b * 2048 + d + k] = (float)r[d + k];
    ctx[(size_t)b * 2048 + ND + d + k] = (float)l[d + k];
  }
}

// ---------------- final projection in f32: out[b,v] = ctx[b,:]@wp[:,v] + bp[v] ----------------
__global__ __launch_bounds__(256) void final_proj_k(
    const float* __restrict__ ctx, const float* __restrict__ wp,
    const float* __restrict__ bp, float* __restrict__ out) {
  const int v = blockIdx.x * 256 + threadIdx.x;
  float acc[NB];
#pragma unroll
  for (int b = 0; b < NB; ++b) acc[b] = 0.f;
  __shared__ float sctx[NB][128];
  for (int k0 = 0; k0 < 2048; k0 += 128) {
    __syncthreads();
    for (int i = threadIdx.x; i < NB * 128; i += 256) {
      int bb = i >> 7, kk = i & 127;
      sctx[bb][kk] = ctx[(size_t)bb * 2048 + k0 + kk];
    }
    __syncthreads();
    for (int kk = 0; kk < 128; ++kk) {
      float wv = wp[(size_t)(k0 + kk) * NV + v];
#pragma unroll
      for (int b = 0; b < NB; ++b) acc[b] += sctx[b][kk] * wv;
    }
  }
#pragma unroll
  for (int b = 0; b < NB; ++b) out[(size_t)b * NV + v] = acc[b] + bp[v];
}

// ---------------- launch ----------------
extern "C" void kernel_launch(void* const* d_in, const int* in_sizes, int n_in,
                              void* d_out, int out_size, void* d_ws, size_t ws_size,
                              hipStream_t stream) {
  const int* x = (const int*)d_in[0];
  const float* emb = (const float*)d_in[1];
  const float* pos = (const float*)d_in[2];
  const float* conv_w = (const float*)d_in[3];
  const float* conv_b = (const float*)d_in[4];
  const float* wg1 = (const float*)d_in[5];
  const float* bg1 = (const float*)d_in[6];
  const float* wmv = (const float*)d_in[7];
  const float* bmv = (const float*)d_in[8];
  const float* wmg = (const float*)d_in[9];
  const float* bmg = (const float*)d_in[10];
  const float* wrg = (const float*)d_in[11];
  const float* brg = (const float*)d_in[12];
  const float* rms_w = (const float*)d_in[13];
  const float* wp = (const float*)d_in[14];
  const float* bp = (const float*)d_in[15];
  float* out = (float*)d_out;

  char* ws = (char*)d_ws;
  size_t off = 0;
  auto alloc = [&](size_t bytes) -> void* {
    void* p = ws + off;
    off += (bytes + 255) & ~(size_t)255;
    return p;
  };
  bf16_t* h0p = (bf16_t*)alloc((size_t)NB * SP * ND * 2);    // conv input, padded
  bf16_t* h = (bf16_t*)alloc((size_t)NB * NS * ND * 2);      // conv output
  bf16_t* nodes = (bf16_t*)alloc((size_t)NB * NS * ND * 2);  // gated nodes (row 2047 dup'd)
  bf16_t* tb0 = (bf16_t*)alloc((size_t)NB * 1024 * ND * 2);
  bf16_t* tb1 = (bf16_t*)alloc((size_t)NB * 1024 * ND * 2);
  bf16_t* convT = (bf16_t*)alloc((size_t)ND * 3072 * 2);
  bf16_t* wg1T = (bf16_t*)alloc((size_t)ND * 1024 * 2);
  bf16_t* wAllT = (bf16_t*)alloc((size_t)3072 * 2048 * 2);  // [wmv^T; wmg^T; wrg^T]
  float* bAll = (float*)alloc((size_t)3072 * 4);
  float* ctx = (float*)alloc((size_t)NB * 2048 * 4);
  if (off > ws_size) return;  // workspace too small: bail (will fail validation visibly)
  // tree logits alias dead conv buffers: bf16 [32768][3072] = 201MB (gemm256 path)
  // or f32 [<=8192][3072] = 100MB (gemm128s path); h0p+h region = 268MB.
  bf16_t* fbuf = (bf16_t*)ws;
  float* fbuf32 = (float*)ws;

  dim3 t256(256), tb32(32, 8);

  // weight conversions (transpose to N x K bf16)
  conv_transpose_k<<<dim3(ND / 32, 3072 / 32), tb32, 0, stream>>>(conv_w, convT, 3072, ND);
  conv_transpose_k<<<dim3(ND / 32, ND / 32), tb32, 0, stream>>>(wg1, wg1T, ND, ND);
  conv_transpose_k<<<dim3(ND / 32, 2048 / 32), tb32, 0, stream>>>(wmv, wAllT, 2048, ND);
  conv_transpose_k<<<dim3(ND / 32, 2048 / 32), tb32, 0, stream>>>(wmg, wAllT + (size_t)1024 * 2048, 2048, ND);
  conv_transpose_k<<<dim3(ND / 32, 2048 / 32), tb32, 0, stream>>>(wrg, wAllT + (size_t)2048 * 2048, 2048, ND);
  concat3_k<<<12, t256, 0, stream>>>(bmv, bmg, brg, bAll);

  zero_pad_k<<<64, t256, 0, stream>>>(h0p);
  embed_k<<<NB * NS, t256, 0, stream>>>(x, emb, pos, h0p);

  // conv as GEMM over contiguous 3*D windows (row remap +2/batch): M=65536 N=1024 K=3072
  gemm256<0><<<1024, 512, 0, stream>>>(h0p, convT, conv_b, nullptr, h,
                                       NB * NS, ND, 3072, ND, 11, 2, 4, 1, 4, 128);
  // nodes = h * sigmoid(h@wg1 + bg1): M=65536 N=1024 K=1024
  gemm256<1><<<1024, 512, 0, stream>>>(h, wg1T, bg1, h, nodes,
                                       NB * NS, ND, ND, ND, 0, 0, 4, 1, 4, 128);
  dup_row_k<<<NB, t256, 0, stream>>>(nodes);  // pad odd level: row 2047 := row 2046

  const bf16_t* cur = nodes;
  bf16_t* bufs[2] = {tb0, tb1};
  int pp = 0;
  for (int L = NS; L > 1; L >>= 1) {
    int M = NB * (L / 2);
    if (M >= 16384) {
      // big level: 256^2 ring-4, bf16 fused logits
      int GY = M / 256;  // 128 or 64 (even)
      gemm256<3><<<12 * GY, 512, 0, stream>>>(cur, wAllT, bAll, nullptr, fbuf,
                                              M, 3072, 2048, 2048, 0, 0, 12, 3, 4, GY / 2);
      tree_combine_k<<<M, t256, 0, stream>>>(fbuf, cur, rms_w, bufs[pp]);
    } else {
      // small level: 128^2 split-K, f32 logits
      int GY = (M + 127) / 128;
      int nxy = 24 * GY;
      int SK = 1;
      while (nxy * SK < 768 && SK < 16) SK <<= 1;
      if (SK > 1) {
        hipMemsetAsync(fbuf32, 0, (size_t)M * 3072 * 4, stream);
        gemm128s<true><<<nxy * SK, t256, 0, stream>>>(cur, wAllT, bAll, fbuf32,
                                                      M, 2048 / SK, nxy);
      } else {
        gemm128s<false><<<nxy, t256, 0, stream>>>(cur, wAllT, bAll, fbuf32, M, 2048, nxy);
      }
      tree_combine32_k<<<M, t256, 0, stream>>>(fbuf32, cur, rms_w, bufs[pp]);
    }
    cur = bufs[pp];
    pp ^= 1;
  }

  build_ctx_k<<<NB, t256, 0, stream>>>(cur, nodes, ctx);
  final_proj_k<<<NV / 256, t256, 0, stream>>>(ctx, wp, bp, out);
}

// Round 8
// 2688.530 us; speedup vs baseline: 1.1488x; 1.0486x over previous
//
#include <hip/hip_runtime.h>
#include <stdint.h>

typedef __bf16 bf16_t;
typedef __attribute__((ext_vector_type(8))) __bf16 bf16x8;
typedef __attribute__((ext_vector_type(4))) __bf16 bf16x4;
typedef __attribute__((ext_vector_type(4))) float f32x4;

#define NB 32
#define NS 2048
#define ND 1024
#define NV 32000
#define SP 2050       // padded rows per batch for conv (1 zero row each side)

__device__ __forceinline__ float sigmoid_(float x) { return 1.0f / (1.0f + __expf(-x)); }

__device__ __forceinline__ void gload_lds16(const void* g, void* lds) {
  __builtin_amdgcn_global_load_lds((const __attribute__((address_space(1))) void*)g,
                                   (__attribute__((address_space(3))) void*)lds, 16, 0, 0);
}

// ---------------- prep / elementwise kernels ----------------

__global__ void zero_pad_k(bf16_t* h0p) {
  int i = blockIdx.x;  // 0..63 : 2 pad rows per batch
  int b = i >> 1;
  size_t row = (size_t)b * SP + ((i & 1) ? (SP - 1) : 0);
  bf16x4 z = {};
  *(bf16x4*)(h0p + row * ND + threadIdx.x * 4) = z;
}

__global__ void embed_k(const int* __restrict__ x, const float* __restrict__ emb,
                        const float* __restrict__ pos, bf16_t* __restrict__ h0p) {
  int bs = blockIdx.x;  // 0..NB*NS-1
  int b = bs >> 11, s = bs & (NS - 1);
  int idx = x[bs];
  const float* e = emb + (size_t)idx * ND;
  const float* p = pos + (size_t)s * ND;
  bf16_t* o = h0p + ((size_t)b * SP + s + 1) * ND;
  int d = threadIdx.x * 4;
  f32x4 ev = *(const f32x4*)(e + d);
  f32x4 pv = *(const f32x4*)(p + d);
  bf16x4 ov;
  ov[0] = (bf16_t)(ev[0] + pv[0]);
  ov[1] = (bf16_t)(ev[1] + pv[1]);
  ov[2] = (bf16_t)(ev[2] + pv[2]);
  ov[3] = (bf16_t)(ev[3] + pv[3]);
  *(bf16x4*)(o + d) = ov;
}

// f32 (R x C) -> bf16 (C x R) transpose+convert, 32x32 LDS tiles
__global__ void conv_transpose_k(const float* __restrict__ in, bf16_t* __restrict__ out,
                                 int R, int C) {
  __shared__ float tile[32][33];
  int tc = blockIdx.x * 32, tr = blockIdx.y * 32;
  int tx = threadIdx.x;
  for (int i = threadIdx.y; i < 32; i += 8)
    tile[i][tx] = in[(size_t)(tr + i) * C + tc + tx];
  __syncthreads();
  for (int i = threadIdx.y; i < 32; i += 8)
    out[(size_t)(tc + i) * R + tr + tx] = (bf16_t)tile[tx][i];
}

__global__ void dup_row_k(bf16_t* nodes) {
  int b = blockIdx.x;
  const bf16_t* src = nodes + ((size_t)b * NS + NS - 2) * ND;
  bf16_t* dst = nodes + ((size_t)b * NS + NS - 1) * ND;
  int d = threadIdx.x * 4;
  *(bf16x4*)(dst + d) = *(const bf16x4*)(src + d);
}

__global__ void concat3_k(const float* __restrict__ a, const float* __restrict__ b,
                          const float* __restrict__ c, float* __restrict__ o) {
  int i = blockIdx.x * 256 + threadIdx.x;  // 0..3071
  o[i] = i < 1024 ? a[i] : (i < 2048 ? b[i - 1024] : c[i - 2048]);
}

// ---------------- 256x256 8-phase GEMM: C = A(MxK, lda) @ Bt(NxK)^T + bias ----------
// BK=64, 512 threads = 8 waves (2M x 4N), per-wave C = 128x64, acc[8][4].
// LDS 128KB: sA/sB[2][256][64] bf16, XOR chunk swizzle (stored chunk c holds
// logical c ^ (row&7)); staged via pre-swizzled global source, linear dest.
// r5-verified phase/barrier/vmcnt structure. NEW: all ds_read byte-offsets and
// stage global pointers hoisted out of the K-loop (t-loop unrolled x2 so buffer
// indices are static) -> near-zero in-loop VALU.
// EPI 0: bf16   1: bf16 aux*sigmoid(v) (GLU)   3: bf16 tree logits
template <int EPI>
__global__ __launch_bounds__(512, 2) void gemm256(
    const bf16_t* __restrict__ A, const bf16_t* __restrict__ Bt,
    const float* __restrict__ bias, const void* aux, void* Cout,
    int M, int N, int K, int lda, int batchShift, int batchPad,
    int GX, int gpx, int nxg, int ych) {
  const int tid = threadIdx.x;
  const int lane = tid & 63;
  const int wave = tid >> 6;
  int n0, m0;
  if (nxg == 0) {  // linear mapping for small grids
    n0 = (blockIdx.x % GX) * 256;
    m0 = (blockIdx.x / GX) * 256;
  } else {  // XCD-partition: xcd owns gpx N-panels + contiguous Y slice
    const int id = blockIdx.x;
    const int xcd = id & 7;
    const int jb = id >> 3;
    const int xg = xcd % nxg;
    const int ysub = xcd / nxg;
    n0 = (xg * gpx + (jb % gpx)) * 256;
    m0 = (ysub * ych + (jb / gpx)) * 256;
  }
  const int waveM = wave >> 2, waveN = wave & 3;

  __shared__ __align__(16) bf16_t sA[2][256 * 64];
  __shared__ __align__(16) bf16_t sB[2][256 * 64];

  // ---- hoisted stage pointers (per lane, K-invariant; advance by 64/tile) ----
  const int srow = tid >> 3;  // 0..63
  const int sj = tid & 7;
  const bf16_t* pA[4];
  const bf16_t* pB[4];
#pragma unroll
  for (int idx = 0; idx < 4; ++idx) {
    int lr = idx * 64 + srow;   // tile row 0..255
    int sc = sj ^ (lr & 7);     // pre-swizzled source chunk
    int gm = m0 + lr;
    if (gm > M - 1) gm = M - 1;
    size_t grow = (size_t)gm + (size_t)(((unsigned)gm) >> batchShift) * batchPad;
    pA[idx] = A + grow * (size_t)lda + sc * 8;
    int gn = n0 + lr;
    if (gn > N - 1) gn = N - 1;
    pB[idx] = Bt + (size_t)gn * K + sc * 8;
  }
  const int ldsrow = wave * 8;  // dest row base per wave

  auto stageA4 = [&](int buf) {  // full A tile (4 instr), advance pointers
#pragma unroll
    for (int idx = 0; idx < 4; ++idx) {
      gload_lds16(pA[idx], &sA[buf][(size_t)(idx * 64 + ldsrow) * 64]);
      pA[idx] += 64;
    }
  };
  auto stageB2 = [&](int buf, int half) {  // half B tile (2 instr)
#pragma unroll
    for (int r = 0; r < 2; ++r) {
      int idx = half * 2 + r;
      gload_lds16(pB[idx], &sB[buf][(size_t)(idx * 64 + ldsrow) * 64]);
      pB[idx] += 64;
    }
  };

  // ---- hoisted ds_read byte offsets (K-invariant) ----
  const int rlane = lane & 15;
  const int klane = lane >> 4;
  int offA[8][2], offB[4][2];
#pragma unroll
  for (int i = 0; i < 8; ++i) {
    int ra = waveM * 128 + i * 16 + rlane;
#pragma unroll
    for (int ks = 0; ks < 2; ++ks)
      offA[i][ks] = ra * 128 + (((ks * 4 + klane) ^ (ra & 7)) << 4);
  }
#pragma unroll
  for (int j = 0; j < 4; ++j) {
    int rb = waveN * 64 + j * 16 + rlane;
#pragma unroll
    for (int ks = 0; ks < 2; ++ks)
      offB[j][ks] = rb * 128 + (((ks * 4 + klane) ^ (rb & 7)) << 4);
  }

  f32x4 acc[8][4] = {};

  const int nt = K >> 6;  // even, >= 16 for all our shapes
  // prologue: A(0),B(0) -> buf0; B(1) -> buf1; wait A(0)+B(0) landed
  stageA4(0);
  stageB2(0, 0); stageB2(0, 1);
  stageB2(1, 0); stageB2(1, 1);
  asm volatile("s_waitcnt vmcnt(4)" ::: "memory");
  __builtin_amdgcn_s_barrier();

  for (int tt = 0; tt < nt; tt += 2) {
#pragma unroll
    for (int u = 0; u < 2; ++u) {  // u static after unroll -> static buffers
      const int t = tt + u;
      bf16x8 bfr[4][2];
#pragma unroll
      for (int p = 0; p < 4; ++p) {
        // ---- ds_read section (precomputed offsets; zero VALU) ----
        if (p == 0) {
#pragma unroll
          for (int j = 0; j < 4; ++j)
#pragma unroll
            for (int ks = 0; ks < 2; ++ks)
              bfr[j][ks] = *(const bf16x8*)((const char*)&sB[u][0] + offB[j][ks]);
        }
        bf16x8 af[2][2];
#pragma unroll
        for (int ii = 0; ii < 2; ++ii)
#pragma unroll
          for (int ks = 0; ks < 2; ++ks)
            af[ii][ks] = *(const bf16x8*)((const char*)&sA[u][0] + offA[p * 2 + ii][ks]);
        // ---- stage section ----
        if (p == 0) {
          if (t + 1 < nt) stageA4(u ^ 1);
        } else if (p == 1) {
          if (t + 2 < nt) stageB2(u, 0);
        } else if (p == 2) {
          if (t + 2 < nt) stageB2(u, 1);
        }
        __builtin_amdgcn_s_barrier();
        // ---- MFMA cluster ----
        __builtin_amdgcn_s_setprio(1);
#pragma unroll
        for (int ks = 0; ks < 2; ++ks)
#pragma unroll
          for (int ii = 0; ii < 2; ++ii)
#pragma unroll
            for (int j = 0; j < 4; ++j)
              acc[p * 2 + ii][j] = __builtin_amdgcn_mfma_f32_16x16x32_bf16(
                  af[ii][ks], bfr[j][ks], acc[p * 2 + ii][j], 0, 0, 0);
        __builtin_amdgcn_s_setprio(0);
        if (p < 3) {
          __builtin_amdgcn_s_barrier();
        } else {
          if (t + 2 < nt)
            asm volatile("s_waitcnt vmcnt(4)" ::: "memory");
          else
            asm volatile("s_waitcnt vmcnt(0)" ::: "memory");
          __builtin_amdgcn_s_barrier();
        }
      }
    }
  }

  // ---- epilogue ----
  const int colBase = n0 + waveN * 64 + rlane;
#pragma unroll
  for (int i = 0; i < 8; ++i) {
    const int rowBase = m0 + waveM * 128 + i * 16 + klane * 4;
#pragma unroll
    for (int j = 0; j < 4; ++j) {
      const int col = colBase + j * 16;
      const float bv = bias[col];
#pragma unroll
      for (int r = 0; r < 4; ++r) {
        const int row = rowBase + r;
        if (row >= M) continue;
        float v = acc[i][j][r] + bv;
        size_t o = (size_t)row * N + col;
        if constexpr (EPI == 0) {
          ((bf16_t*)Cout)[o] = (bf16_t)v;
        } else if constexpr (EPI == 1) {
          float hh = (float)((const bf16_t*)aux)[o];
          ((bf16_t*)Cout)[o] = (bf16_t)(hh * sigmoid_(v));
        } else {
          ((bf16_t*)Cout)[o] = (bf16_t)(col < 1024 ? v : sigmoid_(v));
        }
      }
    }
  }
}

// ---------------- small-M tree GEMM: 128x128 tile, BK=64 dbuf, split-K ----------
// C(f32 logits, N=3072) = A(Mx2048) @ wAllT(3072x2048)^T [+ bias on slice 0]
// Grid: 24 * GY * SK linear. Each block does kLen = 2048/SK of K.
// ATOMIC: atomicAdd partial sums into pre-zeroed fbuf32; else direct store.
template <bool ATOMIC>
__global__ __launch_bounds__(256, 2) void gemm128s(
    const bf16_t* __restrict__ A, const bf16_t* __restrict__ Bt,
    const float* __restrict__ bias, float* __restrict__ Cout,
    int M, int kLen, int nxy) {
  const int tid = threadIdx.x;
  const int lane = tid & 63;
  const int wave = tid >> 6;
  const int id = blockIdx.x;
  const int sk = id / nxy;
  const int rb2 = id % nxy;
  const int n0 = (rb2 % 24) * 128;
  const int m0 = (rb2 / 24) * 128;
  const int kOff = sk * kLen;

  const int waveM = wave >> 1, waveN = wave & 1;

  __shared__ __align__(16) bf16_t sA[2][128 * 64];
  __shared__ __align__(16) bf16_t sB[2][128 * 64];

  f32x4 acc[4][4] = {};

  const int srow = wave * 8 + (lane >> 3);  // + j*32 = tile row staged by this lane
  const int sj = lane & 7;                  // LDS chunk column within row

  auto stage = [&](int buf, int kk0) {
#pragma unroll
    for (int j = 0; j < 4; ++j) {
      int rowT = j * 32 + srow;
      int k8 = sj ^ (rowT & 7);  // pre-swizzled source chunk
      int gm = m0 + rowT;
      if (gm > M - 1) gm = M - 1;
      gload_lds16(A + (size_t)gm * 2048 + (kk0 + k8 * 8), &sA[buf][(j * 256 + wave * 64) * 8]);
      int gn = n0 + rowT;
      gload_lds16(Bt + (size_t)gn * 2048 + (kk0 + k8 * 8), &sB[buf][(j * 256 + wave * 64) * 8]);
    }
  };

  stage(0, kOff);
  __syncthreads();

  const int nt = kLen >> 6;
  int cur = 0;
  const int ar = waveM * 64 + (lane & 15);
  const int br = waveN * 64 + (lane & 15);
  const int kb0 = lane >> 4;

  for (int t = 0; t < nt; ++t) {
    if (t + 1 < nt) stage(cur ^ 1, kOff + (t + 1) * 64);

    const bf16_t* sa = sA[cur];
    const bf16_t* sb = sB[cur];
    bf16x8 af[2][4], bfr[2][4];
#pragma unroll
    for (int ks = 0; ks < 2; ++ks) {
      int kb = kb0 + ks * 4;
#pragma unroll
      for (int i = 0; i < 4; ++i) {
        int ra = ar + i * 16;
        af[ks][i] = *(const bf16x8*)&sa[ra * 64 + ((kb ^ (ra & 7)) * 8)];
        int rbq = br + i * 16;
        bfr[ks][i] = *(const bf16x8*)&sb[rbq * 64 + ((kb ^ (rbq & 7)) * 8)];
      }
    }
#pragma unroll
    for (int ks = 0; ks < 2; ++ks)
#pragma unroll
      for (int i = 0; i < 4; ++i)
#pragma unroll
        for (int j = 0; j < 4; ++j)
          acc[i][j] = __builtin_amdgcn_mfma_f32_16x16x32_bf16(af[ks][i], bfr[ks][j], acc[i][j], 0, 0, 0);
    __syncthreads();
    cur ^= 1;
  }

  const int colBase = n0 + waveN * 64 + (lane & 15);
#pragma unroll
  for (int i = 0; i < 4; ++i) {
    const int rowBase = m0 + waveM * 64 + i * 16 + (lane >> 4) * 4;
#pragma unroll
    for (int jj = 0; jj < 4; ++jj) {
      const int col = colBase + jj * 16;
      const float bv = (!ATOMIC || kOff == 0) ? bias[col] : 0.0f;
#pragma unroll
      for (int r = 0; r < 4; ++r) {
        const int row = rowBase + r;
        if (row >= M) continue;
        float v = acc[i][jj][r] + bv;
        size_t o = (size_t)row * 3072 + col;
        if constexpr (ATOMIC)
          atomicAdd(&Cout[o], v);
        else
          Cout[o] = v;
      }
    }
  }
}

// ---------------- tree combine (bf16 logits path, gemm256): ----------------
// fb row: [0,1024) = val, [1024,2048) = sigmoid(mg), [2048,3072) = sigmoid(rg)
__global__ __launch_bounds__(256) void tree_combine_k(
    const bf16_t* __restrict__ fb, const bf16_t* __restrict__ cur,
    const float* __restrict__ rms_w, bf16_t* __restrict__ outb) {
  const int m = blockIdx.x;
  const int t = threadIdx.x;
  const int d = t * 4;
  const bf16_t* row = fb + (size_t)m * 3072;
  bf16x4 vb = *(const bf16x4*)(row + d);
  bf16x4 gb = *(const bf16x4*)(row + 1024 + d);
  bf16x4 rb = *(const bf16x4*)(row + 2048 + d);
  f32x4 vg;
#pragma unroll
  for (int k = 0; k < 4; ++k) vg[k] = (float)vb[k] * (float)gb[k];
  float ss = vg[0] * vg[0] + vg[1] * vg[1] + vg[2] * vg[2] + vg[3] * vg[3];
#pragma unroll
  for (int o = 32; o > 0; o >>= 1) ss += __shfl_xor(ss, o);
  __shared__ float red[4];
  if ((t & 63) == 0) red[t >> 6] = ss;
  __syncthreads();
  float ms = (red[0] + red[1] + red[2] + red[3]) * (1.0f / ND);
  float scale = rsqrtf(ms + 1.1920929e-07f);
  f32x4 w = *(const f32x4*)(rms_w + d);
  const bf16_t* c0 = cur + (size_t)m * 2048;
  bf16x4 lv = *(const bf16x4*)(c0 + d);
  bf16x4 rv = *(const bf16x4*)(c0 + ND + d);
  bf16x4 o4;
#pragma unroll
  for (int k = 0; k < 4; ++k) {
    float merged = vg[k] * scale * w[k];
    float resid = 0.5f * ((float)lv[k] + (float)rv[k]);
    float g = (float)rb[k];
    o4[k] = (bf16_t)(g * merged + (1.0f - g) * resid);
  }
  *(bf16x4*)(outb + (size_t)m * ND + d) = o4;
}

// ---------------- tree combine (f32 raw logits path, gemm128s): ----------------
// fb row: [0,1024) = val logit, [1024,2048) = mg logit, [2048,3072) = rg logit
__global__ __launch_bounds__(256) void tree_combine32_k(
    const float* __restrict__ fb, const bf16_t* __restrict__ cur,
    const float* __restrict__ rms_w, bf16_t* __restrict__ outb) {
  const int m = blockIdx.x;
  const int t = threadIdx.x;
  const int d = t * 4;
  const float* row = fb + (size_t)m * 3072;
  f32x4 v = *(const f32x4*)(row + d);
  f32x4 gl = *(const f32x4*)(row + 1024 + d);
  f32x4 rl = *(const f32x4*)(row + 2048 + d);
  f32x4 vg;
#pragma unroll
  for (int k = 0; k < 4; ++k) vg[k] = v[k] * sigmoid_(gl[k]);
  float ss = vg[0] * vg[0] + vg[1] * vg[1] + vg[2] * vg[2] + vg[3] * vg[3];
#pragma unroll
  for (int o = 32; o > 0; o >>= 1) ss += __shfl_xor(ss, o);
  __shared__ float red[4];
  if ((t & 63) == 0) red[t >> 6] = ss;
  __syncthreads();
  float ms = (red[0] + red[1] + red[2] + red[3]) * (1.0f / ND);
  float scale = rsqrtf(ms + 1.1920929e-07f);
  f32x4 w = *(const f32x4*)(rms_w + d);
  const bf16_t* c0 = cur + (size_t)m * 2048;
  bf16x4 lv = *(const bf16x4*)(c0 + d);
  bf16x4 rv = *(const bf16x4*)(c0 + ND + d);
  bf16x4 o4;
#pragma unroll
  for (int k = 0; k < 4; ++k) {
    float merged = vg[k] * scale * w[k];
    float resid = 0.5f * ((float)lv[k] + (float)rv[k]);
    float g = sigmoid_(rl[k]);
    o4[k] = (bf16_t)(g * merged + (1.0f - g) * resid);
  }
  *(bf16x4*)(outb + (size_t)m * ND + d) = o4;
}

__global__ void build_ctx_k(const bf16_t* __restrict__ root, const bf16_t* __restrict__ nodes,
                            float* __restrict__ ctx) {
  int b = blockIdx.x, t = threadIdx.x;
  const bf16_t* r = root + (size_t)b * ND;
  const bf16_t* l = nodes + ((size_t)b * NS + NS - 2) * ND;
  int d = t * 4;
#pragma unroll
  for (int k = 0; k < 4; ++k) {
    ctx[(size_t)b * 2048 + d + k] = (float)r[d + k];
    ctx[(size_t)b * 2048 + ND + d + k] = (float)l[d + k];
  }
}

// ---------------- final projection in f32: out[b,v] = ctx[b,:]@wp[:,v] + bp[v] ----------------
__global__ __launch_bounds__(256) void final_proj_k(
    const float* __restrict__ ctx, const float* __restrict__ wp,
    const float* __restrict__ bp, float* __restrict__ out) {
  const int v = blockIdx.x * 256 + threadIdx.x;
  float acc[NB];
#pragma unroll
  for (int b = 0; b < NB; ++b) acc[b] = 0.f;
  __shared__ float sctx[NB][128];
  for (int k0 = 0; k0 < 2048; k0 += 128) {
    __syncthreads();
    for (int i = threadIdx.x; i < NB * 128; i += 256) {
      int bb = i >> 7, kk = i & 127;
      sctx[bb][kk] = ctx[(size_t)bb * 2048 + k0 + kk];
    }
    __syncthreads();
    for (int kk = 0; kk < 128; ++kk) {
      float wv = wp[(size_t)(k0 + kk) * NV + v];
#pragma unroll
      for (int b = 0; b < NB; ++b) acc[b] += sctx[b][kk] * wv;
    }
  }
#pragma unroll
  for (int b = 0; b < NB; ++b) out[(size_t)b * NV + v] = acc[b] + bp[v];
}

// ---------------- launch ----------------
extern "C" void kernel_launch(void* const* d_in, const int* in_sizes, int n_in,
                              void* d_out, int out_size, void* d_ws, size_t ws_size,
                              hipStream_t stream) {
  const int* x = (const int*)d_in[0];
  const float* emb = (const float*)d_in[1];
  const float* pos = (const float*)d_in[2];
  const float* conv_w = (const float*)d_in[3];
  const float* conv_b = (const float*)d_in[4];
  const float* wg1 = (const float*)d_in[5];
  const float* bg1 = (const float*)d_in[6];
  const float* wmv = (const float*)d_in[7];
  const float* bmv = (const float*)d_in[8];
  const float* wmg = (const float*)d_in[9];
  const float* bmg = (const float*)d_in[10];
  const float* wrg = (const float*)d_in[11];
  const float* brg = (const float*)d_in[12];
  const float* rms_w = (const float*)d_in[13];
  const float* wp = (const float*)d_in[14];
  const float* bp = (const float*)d_in[15];
  float* out = (float*)d_out;

  char* ws = (char*)d_ws;
  size_t off = 0;
  auto alloc = [&](size_t bytes) -> void* {
    void* p = ws + off;
    off += (bytes + 255) & ~(size_t)255;
    return p;
  };
  bf16_t* h0p = (bf16_t*)alloc((size_t)NB * SP * ND * 2);    // conv input, padded
  bf16_t* h = (bf16_t*)alloc((size_t)NB * NS * ND * 2);      // conv output
  bf16_t* nodes = (bf16_t*)alloc((size_t)NB * NS * ND * 2);  // gated nodes (row 2047 dup'd)
  bf16_t* tb0 = (bf16_t*)alloc((size_t)NB * 1024 * ND * 2);
  bf16_t* tb1 = (bf16_t*)alloc((size_t)NB * 1024 * ND * 2);
  bf16_t* convT = (bf16_t*)alloc((size_t)ND * 3072 * 2);
  bf16_t* wg1T = (bf16_t*)alloc((size_t)ND * 1024 * 2);
  bf16_t* wAllT = (bf16_t*)alloc((size_t)3072 * 2048 * 2);  // [wmv^T; wmg^T; wrg^T]
  float* bAll = (float*)alloc((size_t)3072 * 4);
  float* ctx = (float*)alloc((size_t)NB * 2048 * 4);
  if (off > ws_size) return;  // workspace too small: bail (will fail validation visibly)
  // tree logits alias dead conv buffers: bf16 [32768][3072] = 201MB (gemm256 path)
  // or f32 [<=8192][3072] = 100MB (gemm128s path); h0p+h region = 268MB.
  bf16_t* fbuf = (bf16_t*)ws;
  float* fbuf32 = (float*)ws;

  dim3 t256(256), tb32(32, 8);

  // weight conversions (transpose to N x K bf16)
  conv_transpose_k<<<dim3(ND / 32, 3072 / 32), tb32, 0, stream>>>(conv_w, convT, 3072, ND);
  conv_transpose_k<<<dim3(ND / 32, ND / 32), tb32, 0, stream>>>(wg1, wg1T, ND, ND);
  conv_transpose_k<<<dim3(ND / 32, 2048 / 32), tb32, 0, stream>>>(wmv, wAllT, 2048, ND);
  conv_transpose_k<<<dim3(ND / 32, 2048 / 32), tb32, 0, stream>>>(wmg, wAllT + (size_t)1024 * 2048, 2048, ND);
  conv_transpose_k<<<dim3(ND / 32, 2048 / 32), tb32, 0, stream>>>(wrg, wAllT + (size_t)2048 * 2048, 2048, ND);
  concat3_k<<<12, t256, 0, stream>>>(bmv, bmg, brg, bAll);

  zero_pad_k<<<64, t256, 0, stream>>>(h0p);
  embed_k<<<NB * NS, t256, 0, stream>>>(x, emb, pos, h0p);

  // conv as GEMM over contiguous 3*D windows (row remap +2/batch): M=65536 N=1024 K=3072
  gemm256<0><<<1024, 512, 0, stream>>>(h0p, convT, conv_b, nullptr, h,
                                       NB * NS, ND, 3072, ND, 11, 2, 4, 1, 4, 128);
  // nodes = h * sigmoid(h@wg1 + bg1): M=65536 N=1024 K=1024
  gemm256<1><<<1024, 512, 0, stream>>>(h, wg1T, bg1, h, nodes,
                                       NB * NS, ND, ND, ND, 0, 0, 4, 1, 4, 128);
  dup_row_k<<<NB, t256, 0, stream>>>(nodes);  // pad odd level: row 2047 := row 2046

  const bf16_t* cur = nodes;
  bf16_t* bufs[2] = {tb0, tb1};
  int pp = 0;
  for (int L = NS; L > 1; L >>= 1) {
    int M = NB * (L / 2);
    if (M >= 16384) {
      // big level: 256^2 8-phase, bf16 fused logits
      int GY = M / 256;  // 128 or 64 (even)
      gemm256<3><<<12 * GY, 512, 0, stream>>>(cur, wAllT, bAll, nullptr, fbuf,
                                              M, 3072, 2048, 2048, 0, 0, 12, 3, 4, GY / 2);
      tree_combine_k<<<M, t256, 0, stream>>>(fbuf, cur, rms_w, bufs[pp]);
    } else {
      // small level: 128^2 split-K, f32 logits
      int GY = (M + 127) / 128;
      int nxy = 24 * GY;
      int SK = 1;
      while (nxy * SK < 768 && SK < 16) SK <<= 1;
      if (SK > 1) {
        hipMemsetAsync(fbuf32, 0, (size_t)M * 3072 * 4, stream);
        gemm128s<true><<<nxy * SK, t256, 0, stream>>>(cur, wAllT, bAll, fbuf32,
                                                      M, 2048 / SK, nxy);
      } else {
        gemm128s<false><<<nxy, t256, 0, stream>>>(cur, wAllT, bAll, fbuf32, M, 2048, nxy);
      }
      tree_combine32_k<<<M, t256, 0, stream>>>(fbuf32, cur, rms_w, bufs[pp]);
    }
    cur = bufs[pp];
    pp ^= 1;
  }

  build_ctx_k<<<NB, t256, 0, stream>>>(cur, nodes, ctx);
  final_proj_k<<<NV / 256, t256, 0, stream>>>(ctx, wp, bp, out);
}

// Round 9
// 2315.208 us; speedup vs baseline: 1.3340x; 1.1612x over previous
//
#include <hip/hip_runtime.h>
#include <stdint.h>

typedef __bf16 bf16_t;
typedef __attribute__((ext_vector_type(8))) __bf16 bf16x8;
typedef __attribute__((ext_vector_type(4))) __bf16 bf16x4;
typedef __attribute__((ext_vector_type(4))) float f32x4;

#define NB 32
#define NS 2048
#define ND 1024
#define NV 32000
#define SP 2050       // padded rows per batch for conv (1 zero row each side)

__device__ __forceinline__ float sigmoid_(float x) { return 1.0f / (1.0f + __expf(-x)); }

__device__ __forceinline__ void gload_lds16(const void* g, void* lds) {
  __builtin_amdgcn_global_load_lds((const __attribute__((address_space(1))) void*)g,
                                   (__attribute__((address_space(3))) void*)lds, 16, 0, 0);
}

// ---------------- prep / elementwise kernels ----------------

__global__ void zero_pad_k(bf16_t* h0p) {
  int i = blockIdx.x;  // 0..63 : 2 pad rows per batch
  int b = i >> 1;
  size_t row = (size_t)b * SP + ((i & 1) ? (SP - 1) : 0);
  bf16x4 z = {};
  *(bf16x4*)(h0p + row * ND + threadIdx.x * 4) = z;
}

__global__ void embed_k(const int* __restrict__ x, const float* __restrict__ emb,
                        const float* __restrict__ pos, bf16_t* __restrict__ h0p) {
  int bs = blockIdx.x;  // 0..NB*NS-1
  int b = bs >> 11, s = bs & (NS - 1);
  int idx = x[bs];
  const float* e = emb + (size_t)idx * ND;
  const float* p = pos + (size_t)s * ND;
  bf16_t* o = h0p + ((size_t)b * SP + s + 1) * ND;
  int d = threadIdx.x * 4;
  f32x4 ev = *(const f32x4*)(e + d);
  f32x4 pv = *(const f32x4*)(p + d);
  bf16x4 ov;
  ov[0] = (bf16_t)(ev[0] + pv[0]);
  ov[1] = (bf16_t)(ev[1] + pv[1]);
  ov[2] = (bf16_t)(ev[2] + pv[2]);
  ov[3] = (bf16_t)(ev[3] + pv[3]);
  *(bf16x4*)(o + d) = ov;
}

// f32 (R x C) -> bf16 (C x R) transpose+convert, 32x32 LDS tiles
__global__ void conv_transpose_k(const float* __restrict__ in, bf16_t* __restrict__ out,
                                 int R, int C) {
  __shared__ float tile[32][33];
  int tc = blockIdx.x * 32, tr = blockIdx.y * 32;
  int tx = threadIdx.x;
  for (int i = threadIdx.y; i < 32; i += 8)
    tile[i][tx] = in[(size_t)(tr + i) * C + tc + tx];
  __syncthreads();
  for (int i = threadIdx.y; i < 32; i += 8)
    out[(size_t)(tc + i) * R + tr + tx] = (bf16_t)tile[tx][i];
}

__global__ void dup_row_k(bf16_t* nodes) {
  int b = blockIdx.x;
  const bf16_t* src = nodes + ((size_t)b * NS + NS - 2) * ND;
  bf16_t* dst = nodes + ((size_t)b * NS + NS - 1) * ND;
  int d = threadIdx.x * 4;
  *(bf16x4*)(dst + d) = *(const bf16x4*)(src + d);
}

__global__ void concat3_k(const float* __restrict__ a, const float* __restrict__ b,
                          const float* __restrict__ c, float* __restrict__ o) {
  int i = blockIdx.x * 256 + threadIdx.x;  // 0..3071
  o[i] = i < 1024 ? a[i] : (i < 2048 ? b[i - 1024] : c[i - 2048]);
}

// ---------------- 256x256 GEMM, BK=64 dbuf, 2 barriers/K-tile ----------------
// 512 threads = 8 waves (2M x 4N), per-wave C = 128x64, acc[8][4].
// LDS 128KB: sA/sB[2][256][64] bf16, XOR chunk swizzle (stored chunk c holds
// logical c ^ (row&7)); staged via pre-swizzled global source, linear dest.
// Per K-tile t (buf u = t&1):
//   issue 8 B-frag ds_reads (sB[u]) ; "" memory fence ; issue 8 A-frag reads
//   s_waitcnt lgkmcnt(8)   -> B reads retired (LDS in-order); A's may be in flight
//   s_barrier (#1)         -> all waves' B reads done
//   stage A4(t+1)->sA[u^1], B4(t+2)->sB[u]   (no read hazard remains)
//   MFMA rows 0-3 ; read A rows 4-7 ; MFMA rows 4-7  (compiler lgkm-interleaves)
//   s_waitcnt vmcnt(4|0) ; s_barrier (#2)   -> A(t+1),B(t+1) landed for next tile
// In-flight ledger (per wave, 4+4 staged/tile): at boundary 12 outstanding,
// vmcnt(4) retires oldest 8 = A(t+1)+B(t+1).  Epilogue tiles: vmcnt(0).
// EPI 0: bf16   1: bf16 aux*sigmoid(v) (GLU)   3: bf16 tree logits
template <int EPI>
__global__ __launch_bounds__(512, 2) void gemm256(
    const bf16_t* __restrict__ A, const bf16_t* __restrict__ Bt,
    const float* __restrict__ bias, const void* aux, void* Cout,
    int M, int N, int K, int lda, int batchShift, int batchPad,
    int GX, int gpx, int nxg, int ych) {
  const int tid = threadIdx.x;
  const int lane = tid & 63;
  const int wave = tid >> 6;
  int n0, m0;
  if (nxg == 0) {  // linear mapping for small grids
    n0 = (blockIdx.x % GX) * 256;
    m0 = (blockIdx.x / GX) * 256;
  } else {  // XCD-partition: xcd owns gpx N-panels + contiguous Y slice
    const int id = blockIdx.x;
    const int xcd = id & 7;
    const int jb = id >> 3;
    const int xg = xcd % nxg;
    const int ysub = xcd / nxg;
    n0 = (xg * gpx + (jb % gpx)) * 256;
    m0 = (ysub * ych + (jb / gpx)) * 256;
  }
  const int waveM = wave >> 2, waveN = wave & 3;

  __shared__ __align__(16) bf16_t sA[2][256 * 64];
  __shared__ __align__(16) bf16_t sB[2][256 * 64];

  // ---- hoisted stage pointers (per lane, K-invariant; advance by 64/tile) ----
  const int srow = tid >> 3;  // 0..63
  const int sj = tid & 7;
  const bf16_t* pA[4];
  const bf16_t* pB[4];
#pragma unroll
  for (int idx = 0; idx < 4; ++idx) {
    int lr = idx * 64 + srow;   // tile row 0..255
    int sc = sj ^ (lr & 7);     // pre-swizzled source chunk
    int gm = m0 + lr;
    if (gm > M - 1) gm = M - 1;
    size_t grow = (size_t)gm + (size_t)(((unsigned)gm) >> batchShift) * batchPad;
    pA[idx] = A + grow * (size_t)lda + sc * 8;
    int gn = n0 + lr;
    if (gn > N - 1) gn = N - 1;
    pB[idx] = Bt + (size_t)gn * K + sc * 8;
  }
  const int ldsrow = wave * 8;  // dest row base per wave

  auto stageA4 = [&](int buf) {
#pragma unroll
    for (int idx = 0; idx < 4; ++idx) {
      gload_lds16(pA[idx], &sA[buf][(size_t)(idx * 64 + ldsrow) * 64]);
      pA[idx] += 64;
    }
  };
  auto stageB4 = [&](int buf) {
#pragma unroll
    for (int idx = 0; idx < 4; ++idx) {
      gload_lds16(pB[idx], &sB[buf][(size_t)(idx * 64 + ldsrow) * 64]);
      pB[idx] += 64;
    }
  };

  // ---- hoisted ds_read byte offsets (K-invariant) ----
  const int rlane = lane & 15;
  const int klane = lane >> 4;
  int offA[8][2], offB[4][2];
#pragma unroll
  for (int i = 0; i < 8; ++i) {
    int ra = waveM * 128 + i * 16 + rlane;
#pragma unroll
    for (int ks = 0; ks < 2; ++ks)
      offA[i][ks] = ra * 128 + (((ks * 4 + klane) ^ (ra & 7)) << 4);
  }
#pragma unroll
  for (int j = 0; j < 4; ++j) {
    int rb = waveN * 64 + j * 16 + rlane;
#pragma unroll
    for (int ks = 0; ks < 2; ++ks)
      offB[j][ks] = rb * 128 + (((ks * 4 + klane) ^ (rb & 7)) << 4);
  }

  f32x4 acc[8][4] = {};

  const int nt = K >> 6;  // even, >= 16 for all our shapes
  // prologue: A(0),B(0) -> buf0; B(1) -> buf1; wait A(0)+B(0) landed
  stageA4(0);
  stageB4(0);
  stageB4(1);
  asm volatile("s_waitcnt vmcnt(4)" ::: "memory");
  __builtin_amdgcn_s_barrier();

  for (int tt = 0; tt < nt; tt += 2) {
#pragma unroll
    for (int u = 0; u < 2; ++u) {  // u static after unroll -> static buffers
      const int t = tt + u;
      // ---- B-frag reads first (pinned order), then A rows 0-3 ----
      bf16x8 bfr[4][2];
#pragma unroll
      for (int j = 0; j < 4; ++j)
#pragma unroll
        for (int ks = 0; ks < 2; ++ks)
          bfr[j][ks] = *(const bf16x8*)((const char*)&sB[u][0] + offB[j][ks]);
      asm volatile("" ::: "memory");  // pin B-read issue before A-reads
      bf16x8 a0[4][2];
#pragma unroll
      for (int i = 0; i < 4; ++i)
#pragma unroll
        for (int ks = 0; ks < 2; ++ks)
          a0[i][ks] = *(const bf16x8*)((const char*)&sA[u][0] + offA[i][ks]);
      asm volatile("s_waitcnt lgkmcnt(8)" ::: "memory");  // B retired (in-order)
      __builtin_amdgcn_s_barrier();  // #1: all waves done reading B
      // ---- stage next tiles (A -> other buf, B(t+2) -> this buf) ----
      if (t + 1 < nt) stageA4(u ^ 1);
      if (t + 2 < nt) stageB4(u);
      // ---- MFMA rows 0-3 ----
      __builtin_amdgcn_s_setprio(1);
#pragma unroll
      for (int ks = 0; ks < 2; ++ks)
#pragma unroll
        for (int i = 0; i < 4; ++i)
#pragma unroll
          for (int j = 0; j < 4; ++j)
            acc[i][j] = __builtin_amdgcn_mfma_f32_16x16x32_bf16(
                a0[i][ks], bfr[j][ks], acc[i][j], 0, 0, 0);
      __builtin_amdgcn_s_setprio(0);
      // ---- A rows 4-7 + MFMA (compiler interleaves via lgkmcnt) ----
      bf16x8 a1[4][2];
#pragma unroll
      for (int i = 0; i < 4; ++i)
#pragma unroll
        for (int ks = 0; ks < 2; ++ks)
          a1[i][ks] = *(const bf16x8*)((const char*)&sA[u][0] + offA[4 + i][ks]);
      __builtin_amdgcn_s_setprio(1);
#pragma unroll
      for (int ks = 0; ks < 2; ++ks)
#pragma unroll
        for (int i = 0; i < 4; ++i)
#pragma unroll
          for (int j = 0; j < 4; ++j)
            acc[4 + i][j] = __builtin_amdgcn_mfma_f32_16x16x32_bf16(
                a1[i][ks], bfr[j][ks], acc[4 + i][j], 0, 0, 0);
      __builtin_amdgcn_s_setprio(0);
      // ---- K-tile boundary ----
      if (t + 2 < nt)
        asm volatile("s_waitcnt vmcnt(4)" ::: "memory");
      else
        asm volatile("s_waitcnt vmcnt(0)" ::: "memory");
      __builtin_amdgcn_s_barrier();  // #2
    }
  }

  // ---- epilogue ----
  const int colBase = n0 + waveN * 64 + rlane;
#pragma unroll
  for (int i = 0; i < 8; ++i) {
    const int rowBase = m0 + waveM * 128 + i * 16 + klane * 4;
#pragma unroll
    for (int j = 0; j < 4; ++j) {
      const int col = colBase + j * 16;
      const float bv = bias[col];
#pragma unroll
      for (int r = 0; r < 4; ++r) {
        const int row = rowBase + r;
        if (row >= M) continue;
        float v = acc[i][j][r] + bv;
        size_t o = (size_t)row * N + col;
        if constexpr (EPI == 0) {
          ((bf16_t*)Cout)[o] = (bf16_t)v;
        } else if constexpr (EPI == 1) {
          float hh = (float)((const bf16_t*)aux)[o];
          ((bf16_t*)Cout)[o] = (bf16_t)(hh * sigmoid_(v));
        } else {
          ((bf16_t*)Cout)[o] = (bf16_t)(col < 1024 ? v : sigmoid_(v));
        }
      }
    }
  }
}

// ---------------- small-M tree GEMM: 128x128 tile, BK=64 dbuf, split-K ----------
template <bool ATOMIC>
__global__ __launch_bounds__(256, 2) void gemm128s(
    const bf16_t* __restrict__ A, const bf16_t* __restrict__ Bt,
    const float* __restrict__ bias, float* __restrict__ Cout,
    int M, int kLen, int nxy) {
  const int tid = threadIdx.x;
  const int lane = tid & 63;
  const int wave = tid >> 6;
  const int id = blockIdx.x;
  const int sk = id / nxy;
  const int rb2 = id % nxy;
  const int n0 = (rb2 % 24) * 128;
  const int m0 = (rb2 / 24) * 128;
  const int kOff = sk * kLen;

  const int waveM = wave >> 1, waveN = wave & 1;

  __shared__ __align__(16) bf16_t sA[2][128 * 64];
  __shared__ __align__(16) bf16_t sB[2][128 * 64];

  f32x4 acc[4][4] = {};

  const int srow = wave * 8 + (lane >> 3);
  const int sj = lane & 7;

  auto stage = [&](int buf, int kk0) {
#pragma unroll
    for (int j = 0; j < 4; ++j) {
      int rowT = j * 32 + srow;
      int k8 = sj ^ (rowT & 7);
      int gm = m0 + rowT;
      if (gm > M - 1) gm = M - 1;
      gload_lds16(A + (size_t)gm * 2048 + (kk0 + k8 * 8), &sA[buf][(j * 256 + wave * 64) * 8]);
      int gn = n0 + rowT;
      gload_lds16(Bt + (size_t)gn * 2048 + (kk0 + k8 * 8), &sB[buf][(j * 256 + wave * 64) * 8]);
    }
  };

  stage(0, kOff);
  __syncthreads();

  const int nt = kLen >> 6;
  int cur = 0;
  const int ar = waveM * 64 + (lane & 15);
  const int br = waveN * 64 + (lane & 15);
  const int kb0 = lane >> 4;

  for (int t = 0; t < nt; ++t) {
    if (t + 1 < nt) stage(cur ^ 1, kOff + (t + 1) * 64);

    const bf16_t* sa = sA[cur];
    const bf16_t* sb = sB[cur];
    bf16x8 af[2][4], bfr[2][4];
#pragma unroll
    for (int ks = 0; ks < 2; ++ks) {
      int kb = kb0 + ks * 4;
#pragma unroll
      for (int i = 0; i < 4; ++i) {
        int ra = ar + i * 16;
        af[ks][i] = *(const bf16x8*)&sa[ra * 64 + ((kb ^ (ra & 7)) * 8)];
        int rbq = br + i * 16;
        bfr[ks][i] = *(const bf16x8*)&sb[rbq * 64 + ((kb ^ (rbq & 7)) * 8)];
      }
    }
#pragma unroll
    for (int ks = 0; ks < 2; ++ks)
#pragma unroll
      for (int i = 0; i < 4; ++i)
#pragma unroll
        for (int j = 0; j < 4; ++j)
          acc[i][j] = __builtin_amdgcn_mfma_f32_16x16x32_bf16(af[ks][i], bfr[ks][j], acc[i][j], 0, 0, 0);
    __syncthreads();
    cur ^= 1;
  }

  const int colBase = n0 + waveN * 64 + (lane & 15);
#pragma unroll
  for (int i = 0; i < 4; ++i) {
    const int rowBase = m0 + waveM * 64 + i * 16 + (lane >> 4) * 4;
#pragma unroll
    for (int jj = 0; jj < 4; ++jj) {
      const int col = colBase + jj * 16;
      const float bv = (!ATOMIC || kOff == 0) ? bias[col] : 0.0f;
#pragma unroll
      for (int r = 0; r < 4; ++r) {
        const int row = rowBase + r;
        if (row >= M) continue;
        float v = acc[i][jj][r] + bv;
        size_t o = (size_t)row * 3072 + col;
        if constexpr (ATOMIC)
          atomicAdd(&Cout[o], v);
        else
          Cout[o] = v;
      }
    }
  }
}

// ---------------- tree combine (bf16 logits path, gemm256): ----------------
__global__ __launch_bounds__(256) void tree_combine_k(
    const bf16_t* __restrict__ fb, const bf16_t* __restrict__ cur,
    const float* __restrict__ rms_w, bf16_t* __restrict__ outb) {
  const int m = blockIdx.x;
  const int t = threadIdx.x;
  const int d = t * 4;
  const bf16_t* row = fb + (size_t)m * 3072;
  bf16x4 vb = *(const bf16x4*)(row + d);
  bf16x4 gb = *(const bf16x4*)(row + 1024 + d);
  bf16x4 rb = *(const bf16x4*)(row + 2048 + d);
  f32x4 vg;
#pragma unroll
  for (int k = 0; k < 4; ++k) vg[k] = (float)vb[k] * (float)gb[k];
  float ss = vg[0] * vg[0] + vg[1] * vg[1] + vg[2] * vg[2] + vg[3] * vg[3];
#pragma unroll
  for (int o = 32; o > 0; o >>= 1) ss += __shfl_xor(ss, o);
  __shared__ float red[4];
  if ((t & 63) == 0) red[t >> 6] = ss;
  __syncthreads();
  float ms = (red[0] + red[1] + red[2] + red[3]) * (1.0f / ND);
  float scale = rsqrtf(ms + 1.1920929e-07f);
  f32x4 w = *(const f32x4*)(rms_w + d);
  const bf16_t* c0 = cur + (size_t)m * 2048;
  bf16x4 lv = *(const bf16x4*)(c0 + d);
  bf16x4 rv = *(const bf16x4*)(c0 + ND + d);
  bf16x4 o4;
#pragma unroll
  for (int k = 0; k < 4; ++k) {
    float merged = vg[k] * scale * w[k];
    float resid = 0.5f * ((float)lv[k] + (float)rv[k]);
    float g = (float)rb[k];
    o4[k] = (bf16_t)(g * merged + (1.0f - g) * resid);
  }
  *(bf16x4*)(outb + (size_t)m * ND + d) = o4;
}

// ---------------- tree combine (f32 raw logits path, gemm128s): ----------------
__global__ __launch_bounds__(256) void tree_combine32_k(
    const float* __restrict__ fb, const bf16_t* __restrict__ cur,
    const float* __restrict__ rms_w, bf16_t* __restrict__ outb) {
  const int m = blockIdx.x;
  const int t = threadIdx.x;
  const int d = t * 4;
  const float* row = fb + (size_t)m * 3072;
  f32x4 v = *(const f32x4*)(row + d);
  f32x4 gl = *(const f32x4*)(row + 1024 + d);
  f32x4 rl = *(const f32x4*)(row + 2048 + d);
  f32x4 vg;
#pragma unroll
  for (int k = 0; k < 4; ++k) vg[k] = v[k] * sigmoid_(gl[k]);
  float ss = vg[0] * vg[0] + vg[1] * vg[1] + vg[2] * vg[2] + vg[3] * vg[3];
#pragma unroll
  for (int o = 32; o > 0; o >>= 1) ss += __shfl_xor(ss, o);
  __shared__ float red[4];
  if ((t & 63) == 0) red[t >> 6] = ss;
  __syncthreads();
  float ms = (red[0] + red[1] + red[2] + red[3]) * (1.0f / ND);
  float scale = rsqrtf(ms + 1.1920929e-07f);
  f32x4 w = *(const f32x4*)(rms_w + d);
  const bf16_t* c0 = cur + (size_t)m * 2048;
  bf16x4 lv = *(const bf16x4*)(c0 + d);
  bf16x4 rv = *(const bf16x4*)(c0 + ND + d);
  bf16x4 o4;
#pragma unroll
  for (int k = 0; k < 4; ++k) {
    float merged = vg[k] * scale * w[k];
    float resid = 0.5f * ((float)lv[k] + (float)rv[k]);
    float g = sigmoid_(rl[k]);
    o4[k] = (bf16_t)(g * merged + (1.0f - g) * resid);
  }
  *(bf16x4*)(outb + (size_t)m * ND + d) = o4;
}

// build bf16 context [root ; last]: ctxb (NB x 2048 bf16)
__global__ void build_ctx_k(const bf16_t* __restrict__ root, const bf16_t* __restrict__ nodes,
                            bf16_t* __restrict__ ctxb) {
  int b = blockIdx.x, t = threadIdx.x;
  const bf16_t* r = root + (size_t)b * ND;
  const bf16_t* l = nodes + ((size_t)b * NS + NS - 2) * ND;
  int d = t * 4;
  *(bf16x4*)(ctxb + (size_t)b * 2048 + d) = *(const bf16x4*)(r + d);
  *(bf16x4*)(ctxb + (size_t)b * 2048 + ND + d) = *(const bf16x4*)(l + d);
}

// out[b][v] = bp[v]  (bias init; atomics accumulate the GEMM)
__global__ void init_out_k(const float* __restrict__ bp, float* __restrict__ out) {
  int i = blockIdx.x * 256 + threadIdx.x;  // 0 .. NB*NV-1 (grid exact)
  int b = i / NV;
  out[i] = bp[i - b * NV];
}

// ---------------- final projection: MFMA, M=32, split-K=4, atomic f32 ----------
// ctxb (32 x 2048 bf16), wpT (NV x 2048 bf16). grid (125, 4), 256 thr = 4 waves.
__global__ __launch_bounds__(256) void proj_gemm_k(
    const bf16_t* __restrict__ ctxb, const bf16_t* __restrict__ wpT,
    float* __restrict__ out) {
  const int lane = threadIdx.x & 63;
  const int wave = threadIdx.x >> 6;
  const int n0 = blockIdx.x * 256 + wave * 64;
  const int kbase = blockIdx.y * 512;
  const int rl = lane & 15, kl = lane >> 4;
  f32x4 acc[2][4] = {};
#pragma unroll 4
  for (int kt = 0; kt < 16; ++kt) {
    const int k0 = kbase + kt * 32 + kl * 8;
    bf16x8 af[2], bfr[4];
#pragma unroll
    for (int i = 0; i < 2; ++i)
      af[i] = *(const bf16x8*)&ctxb[(size_t)(i * 16 + rl) * 2048 + k0];
#pragma unroll
    for (int j = 0; j < 4; ++j)
      bfr[j] = *(const bf16x8*)&wpT[(size_t)(n0 + j * 16 + rl) * 2048 + k0];
#pragma unroll
    for (int i = 0; i < 2; ++i)
#pragma unroll
      for (int j = 0; j < 4; ++j)
        acc[i][j] = __builtin_amdgcn_mfma_f32_16x16x32_bf16(af[i], bfr[j], acc[i][j], 0, 0, 0);
  }
#pragma unroll
  for (int i = 0; i < 2; ++i)
#pragma unroll
    for (int j = 0; j < 4; ++j)
#pragma unroll
      for (int r = 0; r < 4; ++r) {
        int b = i * 16 + kl * 4 + r;
        int v = n0 + j * 16 + rl;
        atomicAdd(&out[(size_t)b * NV + v], acc[i][j][r]);
      }
}

// ---------------- launch ----------------
extern "C" void kernel_launch(void* const* d_in, const int* in_sizes, int n_in,
                              void* d_out, int out_size, void* d_ws, size_t ws_size,
                              hipStream_t stream) {
  const int* x = (const int*)d_in[0];
  const float* emb = (const float*)d_in[1];
  const float* pos = (const float*)d_in[2];
  const float* conv_w = (const float*)d_in[3];
  const float* conv_b = (const float*)d_in[4];
  const float* wg1 = (const float*)d_in[5];
  const float* bg1 = (const float*)d_in[6];
  const float* wmv = (const float*)d_in[7];
  const float* bmv = (const float*)d_in[8];
  const float* wmg = (const float*)d_in[9];
  const float* bmg = (const float*)d_in[10];
  const float* wrg = (const float*)d_in[11];
  const float* brg = (const float*)d_in[12];
  const float* rms_w = (const float*)d_in[13];
  const float* wp = (const float*)d_in[14];
  const float* bp = (const float*)d_in[15];
  float* out = (float*)d_out;

  char* ws = (char*)d_ws;
  size_t off = 0;
  auto alloc = [&](size_t bytes) -> void* {
    void* p = ws + off;
    off += (bytes + 255) & ~(size_t)255;
    return p;
  };
  bf16_t* h0p = (bf16_t*)alloc((size_t)NB * SP * ND * 2);    // conv input, padded
  bf16_t* h = (bf16_t*)alloc((size_t)NB * NS * ND * 2);      // conv output
  bf16_t* nodes = (bf16_t*)alloc((size_t)NB * NS * ND * 2);  // gated nodes (row 2047 dup'd)
  bf16_t* tb0 = (bf16_t*)alloc((size_t)NB * 1024 * ND * 2);
  bf16_t* tb1 = (bf16_t*)alloc((size_t)NB * 1024 * ND * 2);
  bf16_t* convT = (bf16_t*)alloc((size_t)ND * 3072 * 2);
  bf16_t* wg1T = (bf16_t*)alloc((size_t)ND * 1024 * 2);
  bf16_t* wAllT = (bf16_t*)alloc((size_t)3072 * 2048 * 2);  // [wmv^T; wmg^T; wrg^T]
  float* bAll = (float*)alloc((size_t)3072 * 4);
  bf16_t* ctxb = (bf16_t*)alloc((size_t)NB * 2048 * 2);
  if (off > ws_size) return;
  // aliases into the dead conv region [0, 268MB): tree logits (bf16 201MB /
  // f32 <=100MB) during the tree; wpT (131MB bf16) AFTER the tree.
  bf16_t* fbuf = (bf16_t*)ws;
  float* fbuf32 = (float*)ws;
  bf16_t* wpT = (bf16_t*)ws;

  dim3 t256(256), tb32(32, 8);

  // weight conversions (transpose to N x K bf16)
  conv_transpose_k<<<dim3(ND / 32, 3072 / 32), tb32, 0, stream>>>(conv_w, convT, 3072, ND);
  conv_transpose_k<<<dim3(ND / 32, ND / 32), tb32, 0, stream>>>(wg1, wg1T, ND, ND);
  conv_transpose_k<<<dim3(ND / 32, 2048 / 32), tb32, 0, stream>>>(wmv, wAllT, 2048, ND);
  conv_transpose_k<<<dim3(ND / 32, 2048 / 32), tb32, 0, stream>>>(wmg, wAllT + (size_t)1024 * 2048, 2048, ND);
  conv_transpose_k<<<dim3(ND / 32, 2048 / 32), tb32, 0, stream>>>(wrg, wAllT + (size_t)2048 * 2048, 2048, ND);
  concat3_k<<<12, t256, 0, stream>>>(bmv, bmg, brg, bAll);

  zero_pad_k<<<64, t256, 0, stream>>>(h0p);
  embed_k<<<NB * NS, t256, 0, stream>>>(x, emb, pos, h0p);

  // conv as GEMM over contiguous 3*D windows (row remap +2/batch): M=65536 N=1024 K=3072
  gemm256<0><<<1024, 512, 0, stream>>>(h0p, convT, conv_b, nullptr, h,
                                       NB * NS, ND, 3072, ND, 11, 2, 4, 1, 4, 128);
  // nodes = h * sigmoid(h@wg1 + bg1): M=65536 N=1024 K=1024
  gemm256<1><<<1024, 512, 0, stream>>>(h, wg1T, bg1, h, nodes,
                                       NB * NS, ND, ND, ND, 0, 0, 4, 1, 4, 128);
  dup_row_k<<<NB, t256, 0, stream>>>(nodes);  // pad odd level: row 2047 := row 2046

  const bf16_t* cur = nodes;
  bf16_t* bufs[2] = {tb0, tb1};
  int pp = 0;
  for (int L = NS; L > 1; L >>= 1) {
    int M = NB * (L / 2);
    if (M >= 16384) {
      int GY = M / 256;  // 128 or 64 (even)
      gemm256<3><<<12 * GY, 512, 0, stream>>>(cur, wAllT, bAll, nullptr, fbuf,
                                              M, 3072, 2048, 2048, 0, 0, 12, 3, 4, GY / 2);
      tree_combine_k<<<M, t256, 0, stream>>>(fbuf, cur, rms_w, bufs[pp]);
    } else {
      int GY = (M + 127) / 128;
      int nxy = 24 * GY;
      int SK = 1;
      while (nxy * SK < 768 && SK < 16) SK <<= 1;
      if (SK > 1) {
        hipMemsetAsync(fbuf32, 0, (size_t)M * 3072 * 4, stream);
        gemm128s<true><<<nxy * SK, t256, 0, stream>>>(cur, wAllT, bAll, fbuf32,
                                                      M, 2048 / SK, nxy);
      } else {
        gemm128s<false><<<nxy, t256, 0, stream>>>(cur, wAllT, bAll, fbuf32, M, 2048, nxy);
      }
      tree_combine32_k<<<M, t256, 0, stream>>>(fbuf32, cur, rms_w, bufs[pp]);
    }
    cur = bufs[pp];
    pp ^= 1;
  }

  // final projection: wp -> bf16 wpT (into dead conv region), then MFMA split-K
  build_ctx_k<<<NB, t256, 0, stream>>>(cur, nodes, ctxb);
  conv_transpose_k<<<dim3(NV / 32, 2048 / 32), tb32, 0, stream>>>(wp, wpT, 2048, NV);
  init_out_k<<<NB * NV / 256, t256, 0, stream>>>(bp, out);
  proj_gemm_k<<<dim3(NV / 256, 4), t256, 0, stream>>>(ctxb, wpT, out);
}